// Round 7
// baseline (74.674 us; speedup 1.0000x reference)
//
#include <hip/hip_runtime.h>

#define NRAYS 8192
#define NSAMP 173
#define LASTI 172
#define NBLK  (NRAYS / 4)

typedef float f32x4 __attribute__((ext_vector_type(4)));
typedef float f32x2 __attribute__((ext_vector_type(2)));
#define CONST_AS __attribute__((address_space(4)))

__device__ __forceinline__ float wave_sum64(float v) {
#pragma unroll
    for (int off = 32; off > 0; off >>= 1) v += __shfl_xor(v, off, 64);
    return v;
}

__device__ __forceinline__ float RL(float x, int u) {
    return __int_as_float(__builtin_amdgcn_readlane(__float_as_int(x), u));
}

__device__ __forceinline__ float softplus_f(float x) {
    if (x > 15.f) return x;
    return __logf(1.f + __expf(x));
}
__device__ __forceinline__ float sigmoid_f(float x) {
    return 1.f / (1.f + __expf(-x));
}

// ---- prep: fold all weight tables into d_ws (f32), once per launch ----
// layout (float offsets):
//   0    qd4[64]   float4 (Wd1 cols, bd1)
//   256  wd2[64]
//   320  dpack[64] float4 (Wa1 rows 27..29, ba1)
//   576  apA[64]   float4 (wac0, wac1, wac2, Wa2[u][0])   wac = Wapp @ Wa1[:27]
//   832  apB[64]   float2 (Wa2[u][1], Wa2[u][2])
//   960  wscs[60]  1020 bsm[20]  1040 wi[48]  1088 bd2  1089 ba2[3]
//   1100 (as uint) block-completion counter
__global__ void prep_kernel(
    const float* __restrict__ Wd1, const float* __restrict__ bd1,
    const float* __restrict__ Wd2, const float* __restrict__ bd2,
    const float* __restrict__ Wapp, const float* __restrict__ Wa1,
    const float* __restrict__ ba1, const float* __restrict__ Wa2,
    const float* __restrict__ ba2, const float* __restrict__ Wsf,
    const float* __restrict__ Wsm, const float* __restrict__ bsm,
    const float* __restrict__ Wi, float* __restrict__ prep)
{
    const int t = threadIdx.x;
    if (t < 64) {
        ((float4*)prep)[t] = make_float4(Wd1[t], Wd1[64 + t], Wd1[128 + t], bd1[t]);
        prep[256 + t] = Wd2[t];
        ((float4*)(prep + 320))[t] =
            make_float4(Wa1[27 * 64 + t], Wa1[28 * 64 + t], Wa1[29 * 64 + t], ba1[t]);
    } else if (t < 128) {
        int u = t - 64;
        prep[832 + 2 * u]     = Wa2[3 * u + 1];
        prep[832 + 2 * u + 1] = Wa2[3 * u + 2];
    } else if (t < 192) {
        int u = t - 128;
        float s0 = 0.f, s1 = 0.f, s2 = 0.f;
        for (int j = 0; j < 27; ++j) {
            float w = Wa1[j * 64 + u];
            s0 = fmaf(Wapp[j], w, s0);
            s1 = fmaf(Wapp[27 + j], w, s1);
            s2 = fmaf(Wapp[54 + j], w, s2);
        }
        ((float4*)(prep + 576))[u] = make_float4(s0, s1, s2, Wa2[3 * u]);
    } else {
        for (int job = t - 192; job < 132; job += 64) {
            if (job < 60) {
                int m = job / 20, s = job % 20;
                float a = 0.f;
                for (int k = 0; k < 32; ++k) a = fmaf(Wsf[m * 32 + k], Wsm[k * 20 + s], a);
                prep[960 + job] = a;
            } else if (job < 80) {
                prep[1020 + (job - 60)] = bsm[job - 60];
            } else if (job < 128) {
                prep[1040 + (job - 80)] = Wi[job - 80];
            } else if (job == 128) {
                prep[1088] = bd2[0];
            } else {
                prep[1089 + (job - 129)] = ba2[job - 129];
            }
        }
        if (t == 192 + 63) ((unsigned*)prep)[1100] = 0u;  // completion counter
    }
}

__launch_bounds__(256, 4)
__global__ void render_kernel(
    const float* __restrict__ rays,
    const float* __restrict__ prep,
    const int* __restrict__ whitebg_p,
    float* __restrict__ out,
    float* __restrict__ wsdist,
    unsigned* __restrict__ ctr)
{
    __shared__ float sm[256];
    __shared__ int done_flag;

    const int t = threadIdx.x;
    const int wid = t >> 6, lane = t & 63;
    const int r = blockIdx.x * 4 + wid;

    // constant-AS aliases: uniform-index loads through these become s_load (scalar pipe)
    const CONST_AS f32x4* qdC  = (const CONST_AS f32x4*)(unsigned long long)(prep);
    const CONST_AS float* wd2C = (const CONST_AS float*)(unsigned long long)(prep + 256);
    const CONST_AS f32x4* apAC = (const CONST_AS f32x4*)(unsigned long long)(prep + 576);
    const CONST_AS f32x2* apBC = (const CONST_AS f32x2*)(unsigned long long)(prep + 832);
    const CONST_AS float* scC  = (const CONST_AS float*)(unsigned long long)(prep);

    // ray (wave-uniform)
    const float o0 = rays[r * 6 + 0], o1 = rays[r * 6 + 1], o2 = rays[r * 6 + 2];
    const float d0 = rays[r * 6 + 3], d1 = rays[r * 6 + 4], d2 = rays[r * 6 + 5];

    // t_min -- replicate numpy f32 rounding exactly (knife-edge: sample 0 on box face)
    float tm;
    {
        float v0 = (d0 == 0.f) ? 1e-6f : d0;
        float v1 = (d1 == 0.f) ? 1e-6f : d1;
        float v2 = (d2 == 0.f) ? 1e-6f : d2;
        float a0 = __fdiv_rn(__fsub_rn(1.5f, o0), v0), b0 = __fdiv_rn(__fsub_rn(-1.5f, o0), v0);
        float a1 = __fdiv_rn(__fsub_rn(1.5f, o1), v1), b1 = __fdiv_rn(__fsub_rn(-1.5f, o1), v1);
        float a2 = __fdiv_rn(__fsub_rn(1.5f, o2), v2), b2 = __fdiv_rn(__fsub_rn(-1.5f, o2), v2);
        float m0 = fminf(a0, b0), m1 = fminf(a1, b1), m2 = fminf(a2, b2);
        tm = fmaxf(fmaxf(m0, m1), m2);
        tm = fminf(fmaxf(tm, 0.05f), 6.0f);
    }

    // per-ray appearance dconst for unit==lane (lane-distributed; broadcast via readlane in loop)
    float dcr;
    {
        float4 dp = ((const float4*)(prep + 320))[lane];  // divergent index -> normal VMEM
        dcr = fmaf(d2, dp.z, fmaf(d1, dp.y, fmaf(d0, dp.x, dp.w)));
    }

    const float bd2c = scC[1088];
    const float ba2c0 = scC[1089], ba2c1 = scC[1090], ba2c2 = scC[1091];

    const float STEPF = (float)(3.0 / 299.001 * 3.0);
    const float zlast2 = __fadd_rn(tm, __fmul_rn(171.f, STEPF));

    float aR0 = 0.f, aR1 = 0.f, aR2 = 0.f;       // sum w * rgb
    float aS0 = 0.f, aS1 = 0.f, aS2 = 0.f;       // sum masked w * xyzn
    float aSw = 0.f;                             // sum masked w
    float aD = 0.f, aLu = 0.f, aLb = 0.f;        // depth, loss_uni, loss_bi
    float Tc = 1.f, Wcar = 0.f, WMc = 0.f;       // carries

    for (int c = 0; c < 3; ++c) {
        int i = (c << 6) + lane;
        bool valid = i < NSAMP;
        float z = __fadd_rn(tm, __fmul_rn((float)i, STEPF));
        float x0 = __fadd_rn(o0, __fmul_rn(d0, z));
        float x1 = __fadd_rn(o1, __fmul_rn(d1, z));
        float x2 = __fadd_rn(o2, __fmul_rn(d2, z));
        bool inbox = valid && (x0 >= -1.5f) && (x0 <= 1.5f) && (x1 >= -1.5f) && (x1 <= 1.5f) &&
                     (x2 >= -1.5f) && (x2 <= 1.5f);
        if (__ballot(inbox) == 0ull) break;  // in-box span is contiguous from chunk 0

        float xn0 = x0 * (2.f / 3.f), xn1 = x1 * (2.f / 3.f), xn2 = x2 * (2.f / 3.f);

        // density MLP: weights via scalar loads (s_load, scalar pipe overlaps VALU)
        float sp = bd2c;
#pragma unroll 8
        for (int u = 0; u < 64; ++u) {
            f32x4 q = qdC[u];
            float h = fmaf(xn0, q.x, fmaf(xn1, q.y, fmaf(xn2, q.z, q.w)));
            sp = fmaf(fmaxf(h, 0.f), wd2C[u], sp);
        }
        float sigma = inbox ? softplus_f(sp) : 0.f;

        float znext = __fadd_rn(tm, __fmul_rn((float)(i + 1), STEPF));
        float dist = (i < LASTI) ? __fsub_rn(znext, z) : 0.f;
        float alpha = 1.f - __expf(-sigma * dist * 25.f);
        float f = 1.f - alpha + 1e-10f;

        // inclusive product scan of f
        float p = f;
#pragma unroll
        for (int off = 1; off < 64; off <<= 1) {
            float n = __shfl_up(p, off, 64);
            if (lane >= off) p *= n;
        }
        float pex = __shfl_up(p, 1, 64);
        if (lane == 0) pex = 1.f;
        float T = Tc * pex;
        float w = alpha * T;

        float mid = (i < LASTI) ? 0.5f * __fadd_rn(z, znext) : zlast2;
        float wm = w * mid;

        // inclusive sum scans of w, wm
        float sw = w, swm = wm;
#pragma unroll
        for (int off = 1; off < 64; off <<= 1) {
            float n1 = __shfl_up(sw, off, 64);
            float n2 = __shfl_up(swm, off, 64);
            if (lane >= off) { sw += n1; swm += n2; }
        }
        float wex = __shfl_up(sw, 1, 64);
        float wmex = __shfl_up(swm, 1, 64);
        if (lane == 0) { wex = 0.f; wmex = 0.f; }

        aLb += wm * (Wcar + wex) - w * (WMc + wmex);
        aLu = fmaf(dist * w, w, aLu);
        aD = fmaf(w, z, aD);

        Tc *= __shfl(p, 63, 64);
        Wcar += __shfl(sw, 63, 64);
        WMc += __shfl(swm, 63, 64);

        // appearance (only where w > W_THRES)
        float wapp = (w > 1e-4f) ? w : 0.f;
        if (__ballot(wapp > 0.f) != 0ull) {
            float c0 = 0.f, c1 = 0.f, c2 = 0.f;
#pragma unroll 8
            for (int u = 0; u < 64; ++u) {
                f32x4 A = apAC[u];
                f32x2 B = apBC[u];
                float dcu = RL(dcr, u);
                float h = fmaf(xn0, A.x, fmaf(xn1, A.y, fmaf(xn2, A.z, dcu)));
                h = fmaxf(h, 0.f);
                c0 = fmaf(h, A.w, c0);
                c1 = fmaf(h, B.x, c1);
                c2 = fmaf(h, B.y, c2);
            }
            float r0 = sigmoid_f(c0 + ba2c0);
            float r1 = sigmoid_f(c1 + ba2c1);
            float r2 = sigmoid_f(c2 + ba2c2);
            aR0 = fmaf(wapp, r0, aR0);
            aR1 = fmaf(wapp, r1, aR1);
            aR2 = fmaf(wapp, r2, aR2);
            aS0 = fmaf(wapp, xn0, aS0);
            aS1 = fmaf(wapp, xn1, aS1);
            aS2 = fmaf(wapp, xn2, aS2);
            aSw += wapp;
        }

        if (Tc < 1e-8f) break;  // all later weights < 1e-8 << W_THRES
    }

    // wave reductions
    aR0 = wave_sum64(aR0); aR1 = wave_sum64(aR1); aR2 = wave_sum64(aR2);
    aS0 = wave_sum64(aS0); aS1 = wave_sum64(aS1); aS2 = wave_sum64(aS2);
    aSw = wave_sum64(aSw);
    aD = wave_sum64(aD);
    aLu = wave_sum64(aLu);
    aLb = wave_sum64(aLb);

    float opac = Wcar;
    int wb = *whitebg_p;
    float bg = wb ? (1.f - opac) : 0.f;

    float* out_rgb = out;
    float* out_sem = out + 24576;
    float* out_inst = out + 188416;
    float* out_dep = out + 319488;

    if (lane < 3) {
        float rv = (lane == 0 ? aR0 : (lane == 1 ? aR1 : aR2)) + bg;
        rv = fminf(fmaxf(rv, 0.f), 1.f);
        out_rgb[r * 3 + lane] = rv;
    }
    if (lane < 20) {
        float sv = aS0 * prep[960 + lane] + aS1 * prep[980 + lane] + aS2 * prep[1000 + lane] +
                   aSw * prep[1020 + lane];
        out_sem[r * 20 + lane] = sv;
    }
    if (lane < 16) {
        float iv = aS0 * prep[1040 + lane] + aS1 * prep[1056 + lane] + aS2 * prep[1072 + lane];
        out_inst[r * 16 + lane] = iv;
    }
    if (lane == 0) {
        out_dep[r] = aD;
        wsdist[r] = aLu * (1.f / 3.f) + 2.f * aLb;
    }

    // ---- last-block dist_reg reduction (device-scope fence + atomic counter) ----
    __syncthreads();
    if (t == 0) {
        __threadfence();                       // release: make wsdist[r] visible device-wide
        unsigned old = atomicAdd(ctr, 1u);
        done_flag = (old == (unsigned)(NBLK - 1));
    }
    __syncthreads();
    if (done_flag) {
        __threadfence();                       // acquire: see all blocks' wsdist
        float a = 0.f;
        for (int i = t; i < NRAYS; i += 256) a += wsdist[i];
        sm[t] = a;
        __syncthreads();
        for (int st = 128; st > 0; st >>= 1) {
            if (t < st) sm[t] += sm[t + st];
            __syncthreads();
        }
        if (t == 0) {
            out[327680] = sm[0] * (1.f / (float)NRAYS);
            *ctr = 0u;                         // reset for next (graph-replayed) launch
        }
    }
}

extern "C" void kernel_launch(void* const* d_in, const int* in_sizes, int n_in,
                              void* d_out, int out_size, void* d_ws, size_t ws_size,
                              hipStream_t stream) {
    const float* rays = (const float*)d_in[0];
    const float* Wd1  = (const float*)d_in[1];
    const float* bd1  = (const float*)d_in[2];
    const float* Wd2  = (const float*)d_in[3];
    const float* bd2  = (const float*)d_in[4];
    const float* Wapp = (const float*)d_in[5];
    const float* Wa1  = (const float*)d_in[6];
    const float* ba1  = (const float*)d_in[7];
    const float* Wa2  = (const float*)d_in[8];
    const float* ba2  = (const float*)d_in[9];
    const float* Wsf  = (const float*)d_in[10];
    const float* Wsm  = (const float*)d_in[11];
    const float* bsm  = (const float*)d_in[12];
    const float* Wi   = (const float*)d_in[13];
    const int* wb     = (const int*)d_in[15];

    float* out = (float*)d_out;
    float* prep = (float*)d_ws;               // folded tables + counter
    float* wsd  = prep + 2048;                // per-ray dist values
    unsigned* ctr = (unsigned*)prep + 1100;   // completion counter (prep zeroes it)

    prep_kernel<<<1, 256, 0, stream>>>(Wd1, bd1, Wd2, bd2, Wapp, Wa1, ba1, Wa2, ba2,
                                       Wsf, Wsm, bsm, Wi, prep);
    render_kernel<<<NBLK, 256, 0, stream>>>(rays, prep, wb, out, wsd, ctr);
}

// Round 8
// 73.200 us; speedup vs baseline: 1.0201x; 1.0201x over previous
//
#include <hip/hip_runtime.h>

#define NRAYS 8192
#define NSAMP 173
#define LASTI 172
#define NBLK  (NRAYS / 4)

__device__ __forceinline__ float wave_sum64(float v) {
#pragma unroll
    for (int off = 32; off > 0; off >>= 1) v += __shfl_xor(v, off, 64);
    return v;
}

__device__ __forceinline__ float softplus_f(float x) {
    if (x > 15.f) return x;
    return __logf(1.f + __expf(x));
}
__device__ __forceinline__ float sigmoid_f(float x) {
    return 1.f / (1.f + __expf(-x));
}

// ---- prep layout (float offsets into d_ws) ----
//   0 wd1x[64]  64 wd1y[64]  128 wd1z[64]  192 bd1[64]  256 wd2[64]
//   320 wa1d0[64] 384 wa1d1[64] 448 wa1d2[64] 512 ba1[64]
//   576 wac0[64] 640 wac1[64] 704 wac2[64]       (Wapp @ Wa1[:27])
//   768 wa20[64] 832 wa21[64] 896 wa22[64]       (Wa2 columns)
//   960 wscs[60] 1020 bsm[20] 1040 wi[48] 1088 bd2 1089 ba2[3]
//   1100 (uint) completion counter
__global__ void prep_kernel(
    const float* __restrict__ Wd1, const float* __restrict__ bd1,
    const float* __restrict__ Wd2, const float* __restrict__ bd2,
    const float* __restrict__ Wapp, const float* __restrict__ Wa1,
    const float* __restrict__ ba1, const float* __restrict__ Wa2,
    const float* __restrict__ ba2, const float* __restrict__ Wsf,
    const float* __restrict__ Wsm, const float* __restrict__ bsm,
    const float* __restrict__ Wi, float* __restrict__ prep)
{
    const int t = threadIdx.x;
    if (t < 64) {
        prep[t]       = Wd1[t];
        prep[64 + t]  = Wd1[64 + t];
        prep[128 + t] = Wd1[128 + t];
        prep[192 + t] = bd1[t];
        prep[256 + t] = Wd2[t];
        prep[320 + t] = Wa1[27 * 64 + t];
        prep[384 + t] = Wa1[28 * 64 + t];
        prep[448 + t] = Wa1[29 * 64 + t];
        prep[512 + t] = ba1[t];
    } else if (t < 128) {
        int u = t - 64;
        prep[768 + u] = Wa2[3 * u];
        prep[832 + u] = Wa2[3 * u + 1];
        prep[896 + u] = Wa2[3 * u + 2];
    } else if (t < 192) {
        int u = t - 128;
        float s0 = 0.f, s1 = 0.f, s2 = 0.f;
        for (int j = 0; j < 27; ++j) {
            float w = Wa1[j * 64 + u];
            s0 = fmaf(Wapp[j], w, s0);
            s1 = fmaf(Wapp[27 + j], w, s1);
            s2 = fmaf(Wapp[54 + j], w, s2);
        }
        prep[576 + u] = s0;
        prep[640 + u] = s1;
        prep[704 + u] = s2;
    } else {
        for (int job = t - 192; job < 132; job += 64) {
            if (job < 60) {
                int m = job / 20, s = job % 20;
                float a = 0.f;
                for (int k = 0; k < 32; ++k) a = fmaf(Wsf[m * 32 + k], Wsm[k * 20 + s], a);
                prep[960 + job] = a;
            } else if (job < 80) {
                prep[1020 + (job - 60)] = bsm[job - 60];
            } else if (job < 128) {
                prep[1040 + (job - 80)] = Wi[job - 80];
            } else if (job == 128) {
                prep[1088] = bd2[0];
            } else {
                prep[1089 + (job - 129)] = ba2[job - 129];
            }
        }
        if (t == 192 + 63) ((unsigned*)prep)[1100] = 0u;
    }
}

// DPP broadcast folded into v_fmac_f32: one instruction per weight use.
// Weight regs are written once at init (no DPP read-after-VALU-write hazard:
// the DPP-routed operand is never a recently written register).
#define RMASK " row_mask:0xf bank_mask:0xf"

#define DEN1(S, N)                                                                    \
    do {                                                                              \
        float t_;                                                                     \
        asm("v_mov_b32_dpp %[t], %[qw] row_newbcast:" #N RMASK "\n\t"                 \
            "v_fmac_f32_dpp %[t], %[qx], %[x0] row_newbcast:" #N RMASK "\n\t"         \
            "v_fmac_f32_dpp %[t], %[qy], %[x1] row_newbcast:" #N RMASK "\n\t"         \
            "v_fmac_f32_dpp %[t], %[qz], %[x2] row_newbcast:" #N RMASK "\n\t"         \
            "v_max_f32 %[t], 0, %[t]\n\t"                                             \
            "v_fmac_f32_dpp %[sp], %[w2], %[t] row_newbcast:" #N RMASK                \
            : [t] "=&v"(t_), [sp] "+v"(spv)                                           \
            : [qw] "v"(qw[S]), [qx] "v"(qx[S]), [qy] "v"(qy[S]), [qz] "v"(qz[S]),     \
              [w2] "v"(w2[S]), [x0] "v"(xn0), [x1] "v"(xn1), [x2] "v"(xn2));          \
    } while (0)

#define DEN_SET(S)                                                                    \
    DEN1(S, 0); DEN1(S, 1); DEN1(S, 2); DEN1(S, 3); DEN1(S, 4); DEN1(S, 5);           \
    DEN1(S, 6); DEN1(S, 7); DEN1(S, 8); DEN1(S, 9); DEN1(S, 10); DEN1(S, 11);         \
    DEN1(S, 12); DEN1(S, 13); DEN1(S, 14); DEN1(S, 15)

#define APP1(S, N)                                                                    \
    do {                                                                              \
        float t_;                                                                     \
        asm("v_mov_b32_dpp %[t], %[dc] row_newbcast:" #N RMASK "\n\t"                 \
            "v_fmac_f32_dpp %[t], %[a0], %[x0] row_newbcast:" #N RMASK "\n\t"         \
            "v_fmac_f32_dpp %[t], %[a1], %[x1] row_newbcast:" #N RMASK "\n\t"         \
            "v_fmac_f32_dpp %[t], %[a2], %[x2] row_newbcast:" #N RMASK "\n\t"         \
            "v_max_f32 %[t], 0, %[t]\n\t"                                             \
            "v_fmac_f32_dpp %[c0], %[b0], %[t] row_newbcast:" #N RMASK "\n\t"         \
            "v_fmac_f32_dpp %[c1], %[b1], %[t] row_newbcast:" #N RMASK "\n\t"         \
            "v_fmac_f32_dpp %[c2], %[b2], %[t] row_newbcast:" #N RMASK                \
            : [t] "=&v"(t_), [c0] "+v"(c0v), [c1] "+v"(c1v), [c2] "+v"(c2v)           \
            : [dc] "v"(dc[S]), [a0] "v"(a0r[S]), [a1] "v"(a1r[S]), [a2] "v"(a2r[S]),  \
              [b0] "v"(b0r[S]), [b1] "v"(b1r[S]), [b2] "v"(b2r[S]),                   \
              [x0] "v"(xn0), [x1] "v"(xn1), [x2] "v"(xn2));                           \
    } while (0)

#define APP_SET(S)                                                                    \
    APP1(S, 0); APP1(S, 1); APP1(S, 2); APP1(S, 3); APP1(S, 4); APP1(S, 5);           \
    APP1(S, 6); APP1(S, 7); APP1(S, 8); APP1(S, 9); APP1(S, 10); APP1(S, 11);         \
    APP1(S, 12); APP1(S, 13); APP1(S, 14); APP1(S, 15)

__launch_bounds__(256, 2)
__global__ void render_kernel(
    const float* __restrict__ rays,
    const float* __restrict__ prep,
    const int* __restrict__ whitebg_p,
    float* __restrict__ out,
    float* __restrict__ wsdist,
    unsigned* __restrict__ ctr)
{
    __shared__ float sm[256];
    __shared__ int done_flag;

    const int t = threadIdx.x;
    const int wid = t >> 6, lane = t & 63;
    const int r = blockIdx.x * 4 + wid;
    const int k = lane & 15;  // unit-within-set; replicated across the 4 DPP rows

    // ray (wave-uniform)
    const float o0 = rays[r * 6 + 0], o1 = rays[r * 6 + 1], o2 = rays[r * 6 + 2];
    const float d0 = rays[r * 6 + 3], d1 = rays[r * 6 + 4], d2 = rays[r * 6 + 5];

    // ---- weights into VGPRs, row-replicated: lane holds unit 16*S + (lane&15) ----
    float qx[4], qy[4], qz[4], qw[4], w2[4];
    float dc[4], a0r[4], a1r[4], a2r[4], b0r[4], b1r[4], b2r[4];
#pragma unroll
    for (int s = 0; s < 4; ++s) {
        int idx = 16 * s + k;
        qx[s] = prep[idx];
        qy[s] = prep[64 + idx];
        qz[s] = prep[128 + idx];
        qw[s] = prep[192 + idx];
        w2[s] = prep[256 + idx];
        float dcv = prep[512 + idx];
        dcv = fmaf(d0, prep[320 + idx], dcv);
        dcv = fmaf(d1, prep[384 + idx], dcv);
        dcv = fmaf(d2, prep[448 + idx], dcv);
        dc[s] = dcv;
        a0r[s] = prep[576 + idx];
        a1r[s] = prep[640 + idx];
        a2r[s] = prep[704 + idx];
        b0r[s] = prep[768 + idx];
        b1r[s] = prep[832 + idx];
        b2r[s] = prep[896 + idx];
    }

    // t_min -- replicate numpy f32 rounding exactly (knife-edge: sample 0 on box face)
    float tm;
    {
        float v0 = (d0 == 0.f) ? 1e-6f : d0;
        float v1 = (d1 == 0.f) ? 1e-6f : d1;
        float v2 = (d2 == 0.f) ? 1e-6f : d2;
        float a0 = __fdiv_rn(__fsub_rn(1.5f, o0), v0), b0 = __fdiv_rn(__fsub_rn(-1.5f, o0), v0);
        float a1 = __fdiv_rn(__fsub_rn(1.5f, o1), v1), b1 = __fdiv_rn(__fsub_rn(-1.5f, o1), v1);
        float a2 = __fdiv_rn(__fsub_rn(1.5f, o2), v2), b2 = __fdiv_rn(__fsub_rn(-1.5f, o2), v2);
        float m0 = fminf(a0, b0), m1 = fminf(a1, b1), m2 = fminf(a2, b2);
        tm = fmaxf(fmaxf(m0, m1), m2);
        tm = fminf(fmaxf(tm, 0.05f), 6.0f);
    }

    const float bd2c = prep[1088];
    const float ba2c0 = prep[1089], ba2c1 = prep[1090], ba2c2 = prep[1091];

    const float STEPF = (float)(3.0 / 299.001 * 3.0);
    const float zlast2 = __fadd_rn(tm, __fmul_rn(171.f, STEPF));

    float aR0 = 0.f, aR1 = 0.f, aR2 = 0.f;
    float aS0 = 0.f, aS1 = 0.f, aS2 = 0.f;
    float aSw = 0.f;
    float aD = 0.f, aLu = 0.f, aLb = 0.f;
    float Tc = 1.f, Wcar = 0.f, WMc = 0.f;

    for (int c = 0; c < 3; ++c) {
        int i = (c << 6) + lane;
        bool valid = i < NSAMP;
        float z = __fadd_rn(tm, __fmul_rn((float)i, STEPF));
        float x0 = __fadd_rn(o0, __fmul_rn(d0, z));
        float x1 = __fadd_rn(o1, __fmul_rn(d1, z));
        float x2 = __fadd_rn(o2, __fmul_rn(d2, z));
        bool inbox = valid && (x0 >= -1.5f) && (x0 <= 1.5f) && (x1 >= -1.5f) && (x1 <= 1.5f) &&
                     (x2 >= -1.5f) && (x2 <= 1.5f);
        if (__ballot(inbox) == 0ull) break;

        float xn0 = x0 * (2.f / 3.f), xn1 = x1 * (2.f / 3.f), xn2 = x2 * (2.f / 3.f);

        // density MLP: DPP-broadcast weights, 6 VALU per unit, zero memory ops
        float spv = bd2c;
        DEN_SET(0);
        DEN_SET(1);
        DEN_SET(2);
        DEN_SET(3);
        float sigma = inbox ? softplus_f(spv) : 0.f;

        float znext = __fadd_rn(tm, __fmul_rn((float)(i + 1), STEPF));
        float dist = (i < LASTI) ? __fsub_rn(znext, z) : 0.f;
        float alpha = 1.f - __expf(-sigma * dist * 25.f);
        float f = 1.f - alpha + 1e-10f;

        // inclusive product scan of f
        float p = f;
#pragma unroll
        for (int off = 1; off < 64; off <<= 1) {
            float n = __shfl_up(p, off, 64);
            if (lane >= off) p *= n;
        }
        float pex = __shfl_up(p, 1, 64);
        if (lane == 0) pex = 1.f;
        float T = Tc * pex;
        float w = alpha * T;

        float mid = (i < LASTI) ? 0.5f * __fadd_rn(z, znext) : zlast2;
        float wm = w * mid;

        // inclusive sum scans of w, wm
        float sw = w, swm = wm;
#pragma unroll
        for (int off = 1; off < 64; off <<= 1) {
            float n1 = __shfl_up(sw, off, 64);
            float n2 = __shfl_up(swm, off, 64);
            if (lane >= off) { sw += n1; swm += n2; }
        }
        float wex = __shfl_up(sw, 1, 64);
        float wmex = __shfl_up(swm, 1, 64);
        if (lane == 0) { wex = 0.f; wmex = 0.f; }

        aLb += wm * (Wcar + wex) - w * (WMc + wmex);
        aLu = fmaf(dist * w, w, aLu);
        aD = fmaf(w, z, aD);

        Tc *= __shfl(p, 63, 64);
        Wcar += __shfl(sw, 63, 64);
        WMc += __shfl(swm, 63, 64);

        // appearance (only where w > W_THRES)
        float wapp = (w > 1e-4f) ? w : 0.f;
        if (__ballot(wapp > 0.f) != 0ull) {
            float c0v = 0.f, c1v = 0.f, c2v = 0.f;
            APP_SET(0);
            APP_SET(1);
            APP_SET(2);
            APP_SET(3);
            float r0 = sigmoid_f(c0v + ba2c0);
            float r1 = sigmoid_f(c1v + ba2c1);
            float r2 = sigmoid_f(c2v + ba2c2);
            aR0 = fmaf(wapp, r0, aR0);
            aR1 = fmaf(wapp, r1, aR1);
            aR2 = fmaf(wapp, r2, aR2);
            aS0 = fmaf(wapp, xn0, aS0);
            aS1 = fmaf(wapp, xn1, aS1);
            aS2 = fmaf(wapp, xn2, aS2);
            aSw += wapp;
        }

        if (Tc < 1e-8f) break;  // all later weights < 1e-8 << W_THRES
    }

    // wave reductions
    aR0 = wave_sum64(aR0); aR1 = wave_sum64(aR1); aR2 = wave_sum64(aR2);
    aS0 = wave_sum64(aS0); aS1 = wave_sum64(aS1); aS2 = wave_sum64(aS2);
    aSw = wave_sum64(aSw);
    aD = wave_sum64(aD);
    aLu = wave_sum64(aLu);
    aLb = wave_sum64(aLb);

    float opac = Wcar;
    int wb = *whitebg_p;
    float bg = wb ? (1.f - opac) : 0.f;

    float* out_rgb = out;
    float* out_sem = out + 24576;
    float* out_inst = out + 188416;
    float* out_dep = out + 319488;

    if (lane < 3) {
        float rv = (lane == 0 ? aR0 : (lane == 1 ? aR1 : aR2)) + bg;
        rv = fminf(fmaxf(rv, 0.f), 1.f);
        out_rgb[r * 3 + lane] = rv;
    }
    if (lane < 20) {
        float sv = aS0 * prep[960 + lane] + aS1 * prep[980 + lane] + aS2 * prep[1000 + lane] +
                   aSw * prep[1020 + lane];
        out_sem[r * 20 + lane] = sv;
    }
    if (lane < 16) {
        float iv = aS0 * prep[1040 + lane] + aS1 * prep[1056 + lane] + aS2 * prep[1072 + lane];
        out_inst[r * 16 + lane] = iv;
    }
    if (lane == 0) {
        out_dep[r] = aD;
        wsdist[r] = aLu * (1.f / 3.f) + 2.f * aLb;
    }

    // ---- last-block dist_reg reduction ----
    __syncthreads();
    if (t == 0) {
        __threadfence();
        unsigned old = atomicAdd(ctr, 1u);
        done_flag = (old == (unsigned)(NBLK - 1));
    }
    __syncthreads();
    if (done_flag) {
        __threadfence();
        float a = 0.f;
        for (int i = t; i < NRAYS; i += 256) a += wsdist[i];
        sm[t] = a;
        __syncthreads();
        for (int st = 128; st > 0; st >>= 1) {
            if (t < st) sm[t] += sm[t + st];
            __syncthreads();
        }
        if (t == 0) {
            out[327680] = sm[0] * (1.f / (float)NRAYS);
            *ctr = 0u;
        }
    }
}

extern "C" void kernel_launch(void* const* d_in, const int* in_sizes, int n_in,
                              void* d_out, int out_size, void* d_ws, size_t ws_size,
                              hipStream_t stream) {
    const float* rays = (const float*)d_in[0];
    const float* Wd1  = (const float*)d_in[1];
    const float* bd1  = (const float*)d_in[2];
    const float* Wd2  = (const float*)d_in[3];
    const float* bd2  = (const float*)d_in[4];
    const float* Wapp = (const float*)d_in[5];
    const float* Wa1  = (const float*)d_in[6];
    const float* ba1  = (const float*)d_in[7];
    const float* Wa2  = (const float*)d_in[8];
    const float* ba2  = (const float*)d_in[9];
    const float* Wsf  = (const float*)d_in[10];
    const float* Wsm  = (const float*)d_in[11];
    const float* bsm  = (const float*)d_in[12];
    const float* Wi   = (const float*)d_in[13];
    const int* wb     = (const int*)d_in[15];

    float* out = (float*)d_out;
    float* prep = (float*)d_ws;
    float* wsd  = prep + 2048;
    unsigned* ctr = (unsigned*)prep + 1100;

    prep_kernel<<<1, 256, 0, stream>>>(Wd1, bd1, Wd2, bd2, Wapp, Wa1, ba1, Wa2, ba2,
                                       Wsf, Wsm, bsm, Wi, prep);
    render_kernel<<<NBLK, 256, 0, stream>>>(rays, prep, wb, out, wsd, ctr);
}

// Round 9
// 72.093 us; speedup vs baseline: 1.0358x; 1.0154x over previous
//
#include <hip/hip_runtime.h>

#define NRAYS 8192
#define NSAMP 173
#define LASTI 172
#define NBLK  (NRAYS / 4)

__device__ __forceinline__ float wave_sum64(float v) {
#pragma unroll
    for (int off = 32; off > 0; off >>= 1) v += __shfl_xor(v, off, 64);
    return v;
}

__device__ __forceinline__ float softplus_f(float x) {
    if (x > 15.f) return x;
    return __logf(1.f + __expf(x));
}
__device__ __forceinline__ float sigmoid_f(float x) {
    return 1.f / (1.f + __expf(-x));
}

// ---- prep layout (float offsets into d_ws) ----
//   0 wd1x[64]  64 wd1y[64]  128 wd1z[64]  192 bd1[64]  256 wd2[64]
//   320 wa1d0[64] 384 wa1d1[64] 448 wa1d2[64] 512 ba1[64]
//   576 wac0[64] 640 wac1[64] 704 wac2[64]       (Wapp @ Wa1[:27])
//   768 wa20[64] 832 wa21[64] 896 wa22[64]       (Wa2 columns)
//   960 wscs[60] 1020 bsm[20] 1040 wi[48] 1088 bd2 1089 ba2[3]
//   1100 (uint) completion counter
__global__ void prep_kernel(
    const float* __restrict__ Wd1, const float* __restrict__ bd1,
    const float* __restrict__ Wd2, const float* __restrict__ bd2,
    const float* __restrict__ Wapp, const float* __restrict__ Wa1,
    const float* __restrict__ ba1, const float* __restrict__ Wa2,
    const float* __restrict__ ba2, const float* __restrict__ Wsf,
    const float* __restrict__ Wsm, const float* __restrict__ bsm,
    const float* __restrict__ Wi, float* __restrict__ prep)
{
    const int t = threadIdx.x;
    if (t < 64) {
        prep[t]       = Wd1[t];
        prep[64 + t]  = Wd1[64 + t];
        prep[128 + t] = Wd1[128 + t];
        prep[192 + t] = bd1[t];
        prep[256 + t] = Wd2[t];
        prep[320 + t] = Wa1[27 * 64 + t];
        prep[384 + t] = Wa1[28 * 64 + t];
        prep[448 + t] = Wa1[29 * 64 + t];
        prep[512 + t] = ba1[t];
    } else if (t < 128) {
        int u = t - 64;
        prep[768 + u] = Wa2[3 * u];
        prep[832 + u] = Wa2[3 * u + 1];
        prep[896 + u] = Wa2[3 * u + 2];
    } else if (t < 192) {
        int u = t - 128;
        float s0 = 0.f, s1 = 0.f, s2 = 0.f;
        for (int j = 0; j < 27; ++j) {
            float w = Wa1[j * 64 + u];
            s0 = fmaf(Wapp[j], w, s0);
            s1 = fmaf(Wapp[27 + j], w, s1);
            s2 = fmaf(Wapp[54 + j], w, s2);
        }
        prep[576 + u] = s0;
        prep[640 + u] = s1;
        prep[704 + u] = s2;
    } else {
        for (int job = t - 192; job < 132; job += 64) {
            if (job < 60) {
                int m = job / 20, s = job % 20;
                float a = 0.f;
                for (int k = 0; k < 32; ++k) a = fmaf(Wsf[m * 32 + k], Wsm[k * 20 + s], a);
                prep[960 + job] = a;
            } else if (job < 80) {
                prep[1020 + (job - 60)] = bsm[job - 60];
            } else if (job < 128) {
                prep[1040 + (job - 80)] = Wi[job - 80];
            } else if (job == 128) {
                prep[1088] = bd2[0];
            } else {
                prep[1089 + (job - 129)] = ba2[job - 129];
            }
        }
        if (t == 192 + 63) ((unsigned*)prep)[1100] = 0u;
    }
}

#define RMASK " row_mask:0xf bank_mask:0xf"

// 8-way-interleaved DPP density step: units {16s+N0,16s+N1 : s=0..3}.
// Dependent ops are >=8 instructions apart -> DPP latency hidden by ILP.
#define DEN8(N0, N1)                                                                    \
    do {                                                                                \
        float t0, t1, t2, t3, t4, t5, t6, t7;                                           \
        asm("v_mov_b32_dpp %[t0], %[qw0] row_newbcast:" #N0 RMASK "\n\t"                \
            "v_mov_b32_dpp %[t1], %[qw1] row_newbcast:" #N0 RMASK "\n\t"                \
            "v_mov_b32_dpp %[t2], %[qw2] row_newbcast:" #N0 RMASK "\n\t"                \
            "v_mov_b32_dpp %[t3], %[qw3] row_newbcast:" #N0 RMASK "\n\t"                \
            "v_mov_b32_dpp %[t4], %[qw0] row_newbcast:" #N1 RMASK "\n\t"                \
            "v_mov_b32_dpp %[t5], %[qw1] row_newbcast:" #N1 RMASK "\n\t"                \
            "v_mov_b32_dpp %[t6], %[qw2] row_newbcast:" #N1 RMASK "\n\t"                \
            "v_mov_b32_dpp %[t7], %[qw3] row_newbcast:" #N1 RMASK "\n\t"                \
            "v_fmac_f32_dpp %[t0], %[qx0], %[x0] row_newbcast:" #N0 RMASK "\n\t"        \
            "v_fmac_f32_dpp %[t1], %[qx1], %[x0] row_newbcast:" #N0 RMASK "\n\t"        \
            "v_fmac_f32_dpp %[t2], %[qx2], %[x0] row_newbcast:" #N0 RMASK "\n\t"        \
            "v_fmac_f32_dpp %[t3], %[qx3], %[x0] row_newbcast:" #N0 RMASK "\n\t"        \
            "v_fmac_f32_dpp %[t4], %[qx0], %[x0] row_newbcast:" #N1 RMASK "\n\t"        \
            "v_fmac_f32_dpp %[t5], %[qx1], %[x0] row_newbcast:" #N1 RMASK "\n\t"        \
            "v_fmac_f32_dpp %[t6], %[qx2], %[x0] row_newbcast:" #N1 RMASK "\n\t"        \
            "v_fmac_f32_dpp %[t7], %[qx3], %[x0] row_newbcast:" #N1 RMASK "\n\t"        \
            "v_fmac_f32_dpp %[t0], %[qy0], %[x1] row_newbcast:" #N0 RMASK "\n\t"        \
            "v_fmac_f32_dpp %[t1], %[qy1], %[x1] row_newbcast:" #N0 RMASK "\n\t"        \
            "v_fmac_f32_dpp %[t2], %[qy2], %[x1] row_newbcast:" #N0 RMASK "\n\t"        \
            "v_fmac_f32_dpp %[t3], %[qy3], %[x1] row_newbcast:" #N0 RMASK "\n\t"        \
            "v_fmac_f32_dpp %[t4], %[qy0], %[x1] row_newbcast:" #N1 RMASK "\n\t"        \
            "v_fmac_f32_dpp %[t5], %[qy1], %[x1] row_newbcast:" #N1 RMASK "\n\t"        \
            "v_fmac_f32_dpp %[t6], %[qy2], %[x1] row_newbcast:" #N1 RMASK "\n\t"        \
            "v_fmac_f32_dpp %[t7], %[qy3], %[x1] row_newbcast:" #N1 RMASK "\n\t"        \
            "v_fmac_f32_dpp %[t0], %[qz0], %[x2] row_newbcast:" #N0 RMASK "\n\t"        \
            "v_fmac_f32_dpp %[t1], %[qz1], %[x2] row_newbcast:" #N0 RMASK "\n\t"        \
            "v_fmac_f32_dpp %[t2], %[qz2], %[x2] row_newbcast:" #N0 RMASK "\n\t"        \
            "v_fmac_f32_dpp %[t3], %[qz3], %[x2] row_newbcast:" #N0 RMASK "\n\t"        \
            "v_fmac_f32_dpp %[t4], %[qz0], %[x2] row_newbcast:" #N1 RMASK "\n\t"        \
            "v_fmac_f32_dpp %[t5], %[qz1], %[x2] row_newbcast:" #N1 RMASK "\n\t"        \
            "v_fmac_f32_dpp %[t6], %[qz2], %[x2] row_newbcast:" #N1 RMASK "\n\t"        \
            "v_fmac_f32_dpp %[t7], %[qz3], %[x2] row_newbcast:" #N1 RMASK "\n\t"        \
            "v_max_f32 %[t0], 0, %[t0]\n\t"                                             \
            "v_max_f32 %[t1], 0, %[t1]\n\t"                                             \
            "v_max_f32 %[t2], 0, %[t2]\n\t"                                             \
            "v_max_f32 %[t3], 0, %[t3]\n\t"                                             \
            "v_max_f32 %[t4], 0, %[t4]\n\t"                                             \
            "v_max_f32 %[t5], 0, %[t5]\n\t"                                             \
            "v_max_f32 %[t6], 0, %[t6]\n\t"                                             \
            "v_max_f32 %[t7], 0, %[t7]\n\t"                                             \
            "v_fmac_f32_dpp %[s0], %[w20], %[t0] row_newbcast:" #N0 RMASK "\n\t"        \
            "v_fmac_f32_dpp %[s1], %[w21], %[t1] row_newbcast:" #N0 RMASK "\n\t"        \
            "v_fmac_f32_dpp %[s2], %[w22], %[t2] row_newbcast:" #N0 RMASK "\n\t"        \
            "v_fmac_f32_dpp %[s3], %[w23], %[t3] row_newbcast:" #N0 RMASK "\n\t"        \
            "v_fmac_f32_dpp %[s4], %[w20], %[t4] row_newbcast:" #N1 RMASK "\n\t"        \
            "v_fmac_f32_dpp %[s5], %[w21], %[t5] row_newbcast:" #N1 RMASK "\n\t"        \
            "v_fmac_f32_dpp %[s6], %[w22], %[t6] row_newbcast:" #N1 RMASK "\n\t"        \
            "v_fmac_f32_dpp %[s7], %[w23], %[t7] row_newbcast:" #N1 RMASK                \
            : [t0] "=&v"(t0), [t1] "=&v"(t1), [t2] "=&v"(t2), [t3] "=&v"(t3),           \
              [t4] "=&v"(t4), [t5] "=&v"(t5), [t6] "=&v"(t6), [t7] "=&v"(t7),           \
              [s0] "+v"(sps0), [s1] "+v"(sps1), [s2] "+v"(sps2), [s3] "+v"(sps3),       \
              [s4] "+v"(sps4), [s5] "+v"(sps5), [s6] "+v"(sps6), [s7] "+v"(sps7)        \
            : [qw0] "v"(qw[0]), [qw1] "v"(qw[1]), [qw2] "v"(qw[2]), [qw3] "v"(qw[3]),   \
              [qx0] "v"(qx[0]), [qx1] "v"(qx[1]), [qx2] "v"(qx[2]), [qx3] "v"(qx[3]),   \
              [qy0] "v"(qy[0]), [qy1] "v"(qy[1]), [qy2] "v"(qy[2]), [qy3] "v"(qy[3]),   \
              [qz0] "v"(qz[0]), [qz1] "v"(qz[1]), [qz2] "v"(qz[2]), [qz3] "v"(qz[3]),   \
              [w20] "v"(w2[0]), [w21] "v"(w2[1]), [w22] "v"(w2[2]), [w23] "v"(w2[3]),   \
              [x0] "v"(xn0), [x1] "v"(xn1), [x2] "v"(xn2));                             \
    } while (0)

// appearance h for 8 units (interleaved), then fan into 12 c accumulators
#define APP8A(N0, N1)                                                                   \
    asm("v_mov_b32_dpp %[h0], %[dc0] row_newbcast:" #N0 RMASK "\n\t"                    \
        "v_mov_b32_dpp %[h1], %[dc1] row_newbcast:" #N0 RMASK "\n\t"                    \
        "v_mov_b32_dpp %[h2], %[dc2] row_newbcast:" #N0 RMASK "\n\t"                    \
        "v_mov_b32_dpp %[h3], %[dc3] row_newbcast:" #N0 RMASK "\n\t"                    \
        "v_mov_b32_dpp %[h4], %[dc0] row_newbcast:" #N1 RMASK "\n\t"                    \
        "v_mov_b32_dpp %[h5], %[dc1] row_newbcast:" #N1 RMASK "\n\t"                    \
        "v_mov_b32_dpp %[h6], %[dc2] row_newbcast:" #N1 RMASK "\n\t"                    \
        "v_mov_b32_dpp %[h7], %[dc3] row_newbcast:" #N1 RMASK "\n\t"                    \
        "v_fmac_f32_dpp %[h0], %[a00], %[x0] row_newbcast:" #N0 RMASK "\n\t"            \
        "v_fmac_f32_dpp %[h1], %[a01], %[x0] row_newbcast:" #N0 RMASK "\n\t"            \
        "v_fmac_f32_dpp %[h2], %[a02], %[x0] row_newbcast:" #N0 RMASK "\n\t"            \
        "v_fmac_f32_dpp %[h3], %[a03], %[x0] row_newbcast:" #N0 RMASK "\n\t"            \
        "v_fmac_f32_dpp %[h4], %[a00], %[x0] row_newbcast:" #N1 RMASK "\n\t"            \
        "v_fmac_f32_dpp %[h5], %[a01], %[x0] row_newbcast:" #N1 RMASK "\n\t"            \
        "v_fmac_f32_dpp %[h6], %[a02], %[x0] row_newbcast:" #N1 RMASK "\n\t"            \
        "v_fmac_f32_dpp %[h7], %[a03], %[x0] row_newbcast:" #N1 RMASK "\n\t"            \
        "v_fmac_f32_dpp %[h0], %[a10], %[x1] row_newbcast:" #N0 RMASK "\n\t"            \
        "v_fmac_f32_dpp %[h1], %[a11], %[x1] row_newbcast:" #N0 RMASK "\n\t"            \
        "v_fmac_f32_dpp %[h2], %[a12], %[x1] row_newbcast:" #N0 RMASK "\n\t"            \
        "v_fmac_f32_dpp %[h3], %[a13], %[x1] row_newbcast:" #N0 RMASK "\n\t"            \
        "v_fmac_f32_dpp %[h4], %[a10], %[x1] row_newbcast:" #N1 RMASK "\n\t"            \
        "v_fmac_f32_dpp %[h5], %[a11], %[x1] row_newbcast:" #N1 RMASK "\n\t"            \
        "v_fmac_f32_dpp %[h6], %[a12], %[x1] row_newbcast:" #N1 RMASK "\n\t"            \
        "v_fmac_f32_dpp %[h7], %[a13], %[x1] row_newbcast:" #N1 RMASK "\n\t"            \
        "v_fmac_f32_dpp %[h0], %[a20], %[x2] row_newbcast:" #N0 RMASK "\n\t"            \
        "v_fmac_f32_dpp %[h1], %[a21], %[x2] row_newbcast:" #N0 RMASK "\n\t"            \
        "v_fmac_f32_dpp %[h2], %[a22], %[x2] row_newbcast:" #N0 RMASK "\n\t"            \
        "v_fmac_f32_dpp %[h3], %[a23], %[x2] row_newbcast:" #N0 RMASK "\n\t"            \
        "v_fmac_f32_dpp %[h4], %[a20], %[x2] row_newbcast:" #N1 RMASK "\n\t"            \
        "v_fmac_f32_dpp %[h5], %[a21], %[x2] row_newbcast:" #N1 RMASK "\n\t"            \
        "v_fmac_f32_dpp %[h6], %[a22], %[x2] row_newbcast:" #N1 RMASK "\n\t"            \
        "v_fmac_f32_dpp %[h7], %[a23], %[x2] row_newbcast:" #N1 RMASK "\n\t"            \
        "v_max_f32 %[h0], 0, %[h0]\n\t"                                                 \
        "v_max_f32 %[h1], 0, %[h1]\n\t"                                                 \
        "v_max_f32 %[h2], 0, %[h2]\n\t"                                                 \
        "v_max_f32 %[h3], 0, %[h3]\n\t"                                                 \
        "v_max_f32 %[h4], 0, %[h4]\n\t"                                                 \
        "v_max_f32 %[h5], 0, %[h5]\n\t"                                                 \
        "v_max_f32 %[h6], 0, %[h6]\n\t"                                                 \
        "v_max_f32 %[h7], 0, %[h7]"                                                     \
        : [h0] "=&v"(h0), [h1] "=&v"(h1), [h2] "=&v"(h2), [h3] "=&v"(h3),               \
          [h4] "=&v"(h4), [h5] "=&v"(h5), [h6] "=&v"(h6), [h7] "=&v"(h7)                \
        : [dc0] "v"(dc[0]), [dc1] "v"(dc[1]), [dc2] "v"(dc[2]), [dc3] "v"(dc[3]),       \
          [a00] "v"(a0r[0]), [a01] "v"(a0r[1]), [a02] "v"(a0r[2]), [a03] "v"(a0r[3]),   \
          [a10] "v"(a1r[0]), [a11] "v"(a1r[1]), [a12] "v"(a1r[2]), [a13] "v"(a1r[3]),   \
          [a20] "v"(a2r[0]), [a21] "v"(a2r[1]), [a22] "v"(a2r[2]), [a23] "v"(a2r[3]),   \
          [x0] "v"(xn0), [x1] "v"(xn1), [x2] "v"(xn2))

#define APP8B(N0, N1)                                                                   \
    asm("v_fmac_f32_dpp %[c00], %[b00], %[h0] row_newbcast:" #N0 RMASK "\n\t"           \
        "v_fmac_f32_dpp %[c10], %[b10], %[h0] row_newbcast:" #N0 RMASK "\n\t"           \
        "v_fmac_f32_dpp %[c20], %[b20], %[h0] row_newbcast:" #N0 RMASK "\n\t"           \
        "v_fmac_f32_dpp %[c01], %[b01], %[h1] row_newbcast:" #N0 RMASK "\n\t"           \
        "v_fmac_f32_dpp %[c11], %[b11], %[h1] row_newbcast:" #N0 RMASK "\n\t"           \
        "v_fmac_f32_dpp %[c21], %[b21], %[h1] row_newbcast:" #N0 RMASK "\n\t"           \
        "v_fmac_f32_dpp %[c02], %[b02], %[h2] row_newbcast:" #N0 RMASK "\n\t"           \
        "v_fmac_f32_dpp %[c12], %[b12], %[h2] row_newbcast:" #N0 RMASK "\n\t"           \
        "v_fmac_f32_dpp %[c22], %[b22], %[h2] row_newbcast:" #N0 RMASK "\n\t"           \
        "v_fmac_f32_dpp %[c03], %[b03], %[h3] row_newbcast:" #N0 RMASK "\n\t"           \
        "v_fmac_f32_dpp %[c13], %[b13], %[h3] row_newbcast:" #N0 RMASK "\n\t"           \
        "v_fmac_f32_dpp %[c23], %[b23], %[h3] row_newbcast:" #N0 RMASK "\n\t"           \
        "v_fmac_f32_dpp %[c00], %[b00], %[h4] row_newbcast:" #N1 RMASK "\n\t"           \
        "v_fmac_f32_dpp %[c10], %[b10], %[h4] row_newbcast:" #N1 RMASK "\n\t"           \
        "v_fmac_f32_dpp %[c20], %[b20], %[h4] row_newbcast:" #N1 RMASK "\n\t"           \
        "v_fmac_f32_dpp %[c01], %[b01], %[h5] row_newbcast:" #N1 RMASK "\n\t"           \
        "v_fmac_f32_dpp %[c11], %[b11], %[h5] row_newbcast:" #N1 RMASK "\n\t"           \
        "v_fmac_f32_dpp %[c21], %[b21], %[h5] row_newbcast:" #N1 RMASK "\n\t"           \
        "v_fmac_f32_dpp %[c02], %[b02], %[h6] row_newbcast:" #N1 RMASK "\n\t"           \
        "v_fmac_f32_dpp %[c12], %[b12], %[h6] row_newbcast:" #N1 RMASK "\n\t"           \
        "v_fmac_f32_dpp %[c22], %[b22], %[h6] row_newbcast:" #N1 RMASK "\n\t"           \
        "v_fmac_f32_dpp %[c03], %[b03], %[h7] row_newbcast:" #N1 RMASK "\n\t"           \
        "v_fmac_f32_dpp %[c13], %[b13], %[h7] row_newbcast:" #N1 RMASK "\n\t"           \
        "v_fmac_f32_dpp %[c23], %[b23], %[h7] row_newbcast:" #N1 RMASK                   \
        : [c00] "+v"(c00), [c01] "+v"(c01), [c02] "+v"(c02), [c03] "+v"(c03),           \
          [c10] "+v"(c10), [c11] "+v"(c11), [c12] "+v"(c12), [c13] "+v"(c13),           \
          [c20] "+v"(c20), [c21] "+v"(c21), [c22] "+v"(c22), [c23] "+v"(c23)            \
        : [b00] "v"(b0r[0]), [b01] "v"(b0r[1]), [b02] "v"(b0r[2]), [b03] "v"(b0r[3]),   \
          [b10] "v"(b1r[0]), [b11] "v"(b1r[1]), [b12] "v"(b1r[2]), [b13] "v"(b1r[3]),   \
          [b20] "v"(b2r[0]), [b21] "v"(b2r[1]), [b22] "v"(b2r[2]), [b23] "v"(b2r[3]),   \
          [h0] "v"(h0), [h1] "v"(h1), [h2] "v"(h2), [h3] "v"(h3),                       \
          [h4] "v"(h4), [h5] "v"(h5), [h6] "v"(h6), [h7] "v"(h7))

#define APP8(N0, N1) do { float h0,h1,h2,h3,h4,h5,h6,h7; APP8A(N0,N1); APP8B(N0,N1); } while (0)

__launch_bounds__(256, 4)
__global__ void render_kernel(
    const float* __restrict__ rays,
    const float* __restrict__ prep,
    const int* __restrict__ whitebg_p,
    float* __restrict__ out,
    float* __restrict__ wsdist,
    unsigned* __restrict__ ctr)
{
    __shared__ float sm[256];
    __shared__ int done_flag;

    const int t = threadIdx.x;
    const int wid = t >> 6, lane = t & 63;
    const int r = blockIdx.x * 4 + wid;
    const int k = lane & 15;  // unit-within-set; replicated across the 4 DPP rows

    const float o0 = rays[r * 6 + 0], o1 = rays[r * 6 + 1], o2 = rays[r * 6 + 2];
    const float d0 = rays[r * 6 + 3], d1 = rays[r * 6 + 4], d2 = rays[r * 6 + 5];

    // lane holds unit 16*s + (lane&15), replicated within each 16-lane DPP row
    float qx[4], qy[4], qz[4], qw[4], w2[4];
    float dc[4], a0r[4], a1r[4], a2r[4], b0r[4], b1r[4], b2r[4];
#pragma unroll
    for (int s = 0; s < 4; ++s) {
        int idx = 16 * s + k;
        qx[s] = prep[idx];
        qy[s] = prep[64 + idx];
        qz[s] = prep[128 + idx];
        qw[s] = prep[192 + idx];
        w2[s] = prep[256 + idx];
        float dcv = prep[512 + idx];
        dcv = fmaf(d0, prep[320 + idx], dcv);
        dcv = fmaf(d1, prep[384 + idx], dcv);
        dcv = fmaf(d2, prep[448 + idx], dcv);
        dc[s] = dcv;
        a0r[s] = prep[576 + idx];
        a1r[s] = prep[640 + idx];
        a2r[s] = prep[704 + idx];
        b0r[s] = prep[768 + idx];
        b1r[s] = prep[832 + idx];
        b2r[s] = prep[896 + idx];
    }

    // t_min -- replicate numpy f32 rounding exactly (knife-edge: sample 0 on box face)
    float tm;
    {
        float v0 = (d0 == 0.f) ? 1e-6f : d0;
        float v1 = (d1 == 0.f) ? 1e-6f : d1;
        float v2 = (d2 == 0.f) ? 1e-6f : d2;
        float a0 = __fdiv_rn(__fsub_rn(1.5f, o0), v0), b0 = __fdiv_rn(__fsub_rn(-1.5f, o0), v0);
        float a1 = __fdiv_rn(__fsub_rn(1.5f, o1), v1), b1 = __fdiv_rn(__fsub_rn(-1.5f, o1), v1);
        float a2 = __fdiv_rn(__fsub_rn(1.5f, o2), v2), b2 = __fdiv_rn(__fsub_rn(-1.5f, o2), v2);
        float m0 = fminf(a0, b0), m1 = fminf(a1, b1), m2 = fminf(a2, b2);
        tm = fmaxf(fmaxf(m0, m1), m2);
        tm = fminf(fmaxf(tm, 0.05f), 6.0f);
    }

    const float bd2c = prep[1088];
    const float ba2c0 = prep[1089], ba2c1 = prep[1090], ba2c2 = prep[1091];

    const float STEPF = (float)(3.0 / 299.001 * 3.0);
    const float zlast2 = __fadd_rn(tm, __fmul_rn(171.f, STEPF));

    float aR0 = 0.f, aR1 = 0.f, aR2 = 0.f;
    float aS0 = 0.f, aS1 = 0.f, aS2 = 0.f;
    float aSw = 0.f;
    float aD = 0.f, aLu = 0.f, aLb = 0.f;
    float Tc = 1.f, Wcar = 0.f, WMc = 0.f;

    for (int c = 0; c < 3; ++c) {
        int i = (c << 6) + lane;
        bool valid = i < NSAMP;
        float z = __fadd_rn(tm, __fmul_rn((float)i, STEPF));
        float x0 = __fadd_rn(o0, __fmul_rn(d0, z));
        float x1 = __fadd_rn(o1, __fmul_rn(d1, z));
        float x2 = __fadd_rn(o2, __fmul_rn(d2, z));
        bool inbox = valid && (x0 >= -1.5f) && (x0 <= 1.5f) && (x1 >= -1.5f) && (x1 <= 1.5f) &&
                     (x2 >= -1.5f) && (x2 <= 1.5f);
        if (__ballot(inbox) == 0ull) break;

        float xn0 = x0 * (2.f / 3.f), xn1 = x1 * (2.f / 3.f), xn2 = x2 * (2.f / 3.f);

        // density: 8 independent accumulator chains
        float sps0 = bd2c, sps1 = 0.f, sps2 = 0.f, sps3 = 0.f;
        float sps4 = 0.f, sps5 = 0.f, sps6 = 0.f, sps7 = 0.f;
        DEN8(0, 1);  DEN8(2, 3);  DEN8(4, 5);  DEN8(6, 7);
        DEN8(8, 9);  DEN8(10, 11); DEN8(12, 13); DEN8(14, 15);
        float spv = ((sps0 + sps1) + (sps2 + sps3)) + ((sps4 + sps5) + (sps6 + sps7));
        float sigma = inbox ? softplus_f(spv) : 0.f;

        float znext = __fadd_rn(tm, __fmul_rn((float)(i + 1), STEPF));
        float dist = (i < LASTI) ? __fsub_rn(znext, z) : 0.f;
        float alpha = 1.f - __expf(-sigma * dist * 25.f);
        float f = 1.f - alpha + 1e-10f;

        // inclusive product scan of f
        float p = f;
#pragma unroll
        for (int off = 1; off < 64; off <<= 1) {
            float n = __shfl_up(p, off, 64);
            if (lane >= off) p *= n;
        }
        float pex = __shfl_up(p, 1, 64);
        if (lane == 0) pex = 1.f;
        float T = Tc * pex;
        float w = alpha * T;

        float mid = (i < LASTI) ? 0.5f * __fadd_rn(z, znext) : zlast2;
        float wm = w * mid;

        // inclusive sum scans of w, wm
        float sw = w, swm = wm;
#pragma unroll
        for (int off = 1; off < 64; off <<= 1) {
            float n1 = __shfl_up(sw, off, 64);
            float n2 = __shfl_up(swm, off, 64);
            if (lane >= off) { sw += n1; swm += n2; }
        }
        float wex = __shfl_up(sw, 1, 64);
        float wmex = __shfl_up(swm, 1, 64);
        if (lane == 0) { wex = 0.f; wmex = 0.f; }

        aLb += wm * (Wcar + wex) - w * (WMc + wmex);
        aLu = fmaf(dist * w, w, aLu);
        aD = fmaf(w, z, aD);

        Tc *= __shfl(p, 63, 64);
        Wcar += __shfl(sw, 63, 64);
        WMc += __shfl(swm, 63, 64);

        // appearance (only where w > W_THRES)
        float wapp = (w > 1e-4f) ? w : 0.f;
        if (__ballot(wapp > 0.f) != 0ull) {
            float c00 = 0.f, c01 = 0.f, c02 = 0.f, c03 = 0.f;
            float c10 = 0.f, c11 = 0.f, c12 = 0.f, c13 = 0.f;
            float c20 = 0.f, c21 = 0.f, c22 = 0.f, c23 = 0.f;
            APP8(0, 1);  APP8(2, 3);  APP8(4, 5);  APP8(6, 7);
            APP8(8, 9);  APP8(10, 11); APP8(12, 13); APP8(14, 15);
            float c0v = (c00 + c01) + (c02 + c03);
            float c1v = (c10 + c11) + (c12 + c13);
            float c2v = (c20 + c21) + (c22 + c23);
            float r0 = sigmoid_f(c0v + ba2c0);
            float r1 = sigmoid_f(c1v + ba2c1);
            float r2 = sigmoid_f(c2v + ba2c2);
            aR0 = fmaf(wapp, r0, aR0);
            aR1 = fmaf(wapp, r1, aR1);
            aR2 = fmaf(wapp, r2, aR2);
            aS0 = fmaf(wapp, xn0, aS0);
            aS1 = fmaf(wapp, xn1, aS1);
            aS2 = fmaf(wapp, xn2, aS2);
            aSw += wapp;
        }

        if (Tc < 1e-8f) break;  // all later weights < 1e-8 << W_THRES
    }

    // wave reductions
    aR0 = wave_sum64(aR0); aR1 = wave_sum64(aR1); aR2 = wave_sum64(aR2);
    aS0 = wave_sum64(aS0); aS1 = wave_sum64(aS1); aS2 = wave_sum64(aS2);
    aSw = wave_sum64(aSw);
    aD = wave_sum64(aD);
    aLu = wave_sum64(aLu);
    aLb = wave_sum64(aLb);

    float opac = Wcar;
    int wb = *whitebg_p;
    float bg = wb ? (1.f - opac) : 0.f;

    float* out_rgb = out;
    float* out_sem = out + 24576;
    float* out_inst = out + 188416;
    float* out_dep = out + 319488;

    if (lane < 3) {
        float rv = (lane == 0 ? aR0 : (lane == 1 ? aR1 : aR2)) + bg;
        rv = fminf(fmaxf(rv, 0.f), 1.f);
        out_rgb[r * 3 + lane] = rv;
    }
    if (lane < 20) {
        float sv = aS0 * prep[960 + lane] + aS1 * prep[980 + lane] + aS2 * prep[1000 + lane] +
                   aSw * prep[1020 + lane];
        out_sem[r * 20 + lane] = sv;
    }
    if (lane < 16) {
        float iv = aS0 * prep[1040 + lane] + aS1 * prep[1056 + lane] + aS2 * prep[1072 + lane];
        out_inst[r * 16 + lane] = iv;
    }
    if (lane == 0) {
        out_dep[r] = aD;
        wsdist[r] = aLu * (1.f / 3.f) + 2.f * aLb;
    }

    // ---- last-block dist_reg reduction ----
    __syncthreads();
    if (t == 0) {
        __threadfence();
        unsigned old = atomicAdd(ctr, 1u);
        done_flag = (old == (unsigned)(NBLK - 1));
    }
    __syncthreads();
    if (done_flag) {
        __threadfence();
        float a = 0.f;
        for (int i = t; i < NRAYS; i += 256) a += wsdist[i];
        sm[t] = a;
        __syncthreads();
        for (int st = 128; st > 0; st >>= 1) {
            if (t < st) sm[t] += sm[t + st];
            __syncthreads();
        }
        if (t == 0) {
            out[327680] = sm[0] * (1.f / (float)NRAYS);
            *ctr = 0u;
        }
    }
}

extern "C" void kernel_launch(void* const* d_in, const int* in_sizes, int n_in,
                              void* d_out, int out_size, void* d_ws, size_t ws_size,
                              hipStream_t stream) {
    const float* rays = (const float*)d_in[0];
    const float* Wd1  = (const float*)d_in[1];
    const float* bd1  = (const float*)d_in[2];
    const float* Wd2  = (const float*)d_in[3];
    const float* bd2  = (const float*)d_in[4];
    const float* Wapp = (const float*)d_in[5];
    const float* Wa1  = (const float*)d_in[6];
    const float* ba1  = (const float*)d_in[7];
    const float* Wa2  = (const float*)d_in[8];
    const float* ba2  = (const float*)d_in[9];
    const float* Wsf  = (const float*)d_in[10];
    const float* Wsm  = (const float*)d_in[11];
    const float* bsm  = (const float*)d_in[12];
    const float* Wi   = (const float*)d_in[13];
    const int* wb     = (const int*)d_in[15];

    float* out = (float*)d_out;
    float* prep = (float*)d_ws;
    float* wsd  = prep + 2048;
    unsigned* ctr = (unsigned*)prep + 1100;

    prep_kernel<<<1, 256, 0, stream>>>(Wd1, bd1, Wd2, bd2, Wapp, Wa1, ba1, Wa2, ba2,
                                       Wsf, Wsm, bsm, Wi, prep);
    render_kernel<<<NBLK, 256, 0, stream>>>(rays, prep, wb, out, wsd, ctr);
}

// Round 10
// 36.431 us; speedup vs baseline: 2.0497x; 1.9789x over previous
//
#include <hip/hip_runtime.h>

#define NRAYS 8192
#define NSAMP 173
#define LASTI 172
#define NBLK  (NRAYS / 4)

__device__ __forceinline__ float wave_sum64(float v) {
#pragma unroll
    for (int off = 32; off > 0; off >>= 1) v += __shfl_xor(v, off, 64);
    return v;
}

__device__ __forceinline__ float RL(float x, int u) {
    return __int_as_float(__builtin_amdgcn_readlane(__float_as_int(x), u));
}

__device__ __forceinline__ float softplus_f(float x) {
    if (x > 15.f) return x;
    return __logf(1.f + __expf(x));
}
__device__ __forceinline__ float sigmoid_f(float x) {
    return 1.f / (1.f + __expf(-x));
}

// ---- prep layout (float offsets into d_ws), same as R7 ----
//   0    qd4[64]   float4 (Wd1 cols, bd1)
//   256  wd2[64]
//   320  dpack[64] float4 (Wa1 rows 27..29, ba1)
//   576  apA[64]   float4 (wac0, wac1, wac2, Wa2[u][0])   wac = Wapp @ Wa1[:27]
//   832  apB[64]   float2 (Wa2[u][1], Wa2[u][2])
//   960  wscs[60]  1020 bsm[20]  1040 wi[48]  1088 bd2  1089 ba2[3]
__global__ void prep_kernel(
    const float* __restrict__ Wd1, const float* __restrict__ bd1,
    const float* __restrict__ Wd2, const float* __restrict__ bd2,
    const float* __restrict__ Wapp, const float* __restrict__ Wa1,
    const float* __restrict__ ba1, const float* __restrict__ Wa2,
    const float* __restrict__ ba2, const float* __restrict__ Wsf,
    const float* __restrict__ Wsm, const float* __restrict__ bsm,
    const float* __restrict__ Wi, float* __restrict__ prep)
{
    const int t = threadIdx.x;
    if (t < 64) {
        ((float4*)prep)[t] = make_float4(Wd1[t], Wd1[64 + t], Wd1[128 + t], bd1[t]);
        prep[256 + t] = Wd2[t];
        ((float4*)(prep + 320))[t] =
            make_float4(Wa1[27 * 64 + t], Wa1[28 * 64 + t], Wa1[29 * 64 + t], ba1[t]);
    } else if (t < 128) {
        int u = t - 64;
        prep[832 + 2 * u]     = Wa2[3 * u + 1];
        prep[832 + 2 * u + 1] = Wa2[3 * u + 2];
    } else if (t < 192) {
        int u = t - 128;
        float s0 = 0.f, s1 = 0.f, s2 = 0.f;
        for (int j = 0; j < 27; ++j) {
            float w = Wa1[j * 64 + u];
            s0 = fmaf(Wapp[j], w, s0);
            s1 = fmaf(Wapp[27 + j], w, s1);
            s2 = fmaf(Wapp[54 + j], w, s2);
        }
        ((float4*)(prep + 576))[u] = make_float4(s0, s1, s2, Wa2[3 * u]);
    } else {
        for (int job = t - 192; job < 132; job += 64) {
            if (job < 60) {
                int m = job / 20, s = job % 20;
                float a = 0.f;
                for (int k = 0; k < 32; ++k) a = fmaf(Wsf[m * 32 + k], Wsm[k * 20 + s], a);
                prep[960 + job] = a;
            } else if (job < 80) {
                prep[1020 + (job - 60)] = bsm[job - 60];
            } else if (job < 128) {
                prep[1040 + (job - 80)] = Wi[job - 80];
            } else if (job == 128) {
                prep[1088] = bd2[0];
            } else {
                prep[1089 + (job - 129)] = ba2[job - 129];
            }
        }
    }
}

__launch_bounds__(256, 4)
__global__ void render_kernel(
    const float* __restrict__ rays,
    const float* __restrict__ prep,
    const int* __restrict__ whitebg_p,
    float* __restrict__ out,
    float* __restrict__ wsdist)
{
    // density weights via LDS (ds pipe); appearance via VMEM (TA pipe)
    __shared__ float4 qd4[64];
    __shared__ float  wd2s[64];

    const int t = threadIdx.x;
    const int wid = t >> 6, lane = t & 63;
    const int r = blockIdx.x * 4 + wid;

    if (t < 64) {
        qd4[t] = ((const float4*)prep)[t];
        wd2s[t] = prep[256 + t];
    }

    const float4* __restrict__ apAg = (const float4*)(prep + 576);
    const float2* __restrict__ apBg = (const float2*)(prep + 832);

    // ray (wave-uniform)
    const float o0 = rays[r * 6 + 0], o1 = rays[r * 6 + 1], o2 = rays[r * 6 + 2];
    const float d0 = rays[r * 6 + 3], d1 = rays[r * 6 + 4], d2 = rays[r * 6 + 5];

    // t_min -- replicate numpy f32 rounding exactly (knife-edge: sample 0 on box face)
    float tm;
    {
        float v0 = (d0 == 0.f) ? 1e-6f : d0;
        float v1 = (d1 == 0.f) ? 1e-6f : d1;
        float v2 = (d2 == 0.f) ? 1e-6f : d2;
        float a0 = __fdiv_rn(__fsub_rn(1.5f, o0), v0), b0 = __fdiv_rn(__fsub_rn(-1.5f, o0), v0);
        float a1 = __fdiv_rn(__fsub_rn(1.5f, o1), v1), b1 = __fdiv_rn(__fsub_rn(-1.5f, o1), v1);
        float a2 = __fdiv_rn(__fsub_rn(1.5f, o2), v2), b2 = __fdiv_rn(__fsub_rn(-1.5f, o2), v2);
        float m0 = fminf(a0, b0), m1 = fminf(a1, b1), m2 = fminf(a2, b2);
        tm = fmaxf(fmaxf(m0, m1), m2);
        tm = fminf(fmaxf(tm, 0.05f), 6.0f);
    }

    // per-ray appearance dconst for unit==lane (lane-distributed; broadcast via readlane)
    float dcr;
    {
        float4 dp = ((const float4*)(prep + 320))[lane];
        dcr = fmaf(d2, dp.z, fmaf(d1, dp.y, fmaf(d0, dp.x, dp.w)));
    }
    __syncthreads();

    const float bd2c = prep[1088];
    const float ba2c0 = prep[1089], ba2c1 = prep[1090], ba2c2 = prep[1091];

    const float STEPF = (float)(3.0 / 299.001 * 3.0);
    const float zlast2 = __fadd_rn(tm, __fmul_rn(171.f, STEPF));

    float aR0 = 0.f, aR1 = 0.f, aR2 = 0.f;
    float aS0 = 0.f, aS1 = 0.f, aS2 = 0.f;
    float aSw = 0.f;
    float aD = 0.f, aLu = 0.f, aLb = 0.f;
    float Tc = 1.f, Wcar = 0.f, WMc = 0.f;

    // =========== PASS 1: samples 0..127, two per lane, ONE weight fetch ===========
    {
        const int iA = lane, iB = 64 + lane;
        float zA = __fadd_rn(tm, __fmul_rn((float)iA, STEPF));
        float zB = __fadd_rn(tm, __fmul_rn((float)iB, STEPF));
        float xA0 = __fadd_rn(o0, __fmul_rn(d0, zA));
        float xA1 = __fadd_rn(o1, __fmul_rn(d1, zA));
        float xA2 = __fadd_rn(o2, __fmul_rn(d2, zA));
        float xB0 = __fadd_rn(o0, __fmul_rn(d0, zB));
        float xB1 = __fadd_rn(o1, __fmul_rn(d1, zB));
        float xB2 = __fadd_rn(o2, __fmul_rn(d2, zB));
        bool inA = (xA0 >= -1.5f) && (xA0 <= 1.5f) && (xA1 >= -1.5f) && (xA1 <= 1.5f) &&
                   (xA2 >= -1.5f) && (xA2 <= 1.5f);
        bool inB = (xB0 >= -1.5f) && (xB0 <= 1.5f) && (xB1 >= -1.5f) && (xB1 <= 1.5f) &&
                   (xB2 >= -1.5f) && (xB2 <= 1.5f);

        float xnA0 = xA0 * (2.f / 3.f), xnA1 = xA1 * (2.f / 3.f), xnA2 = xA2 * (2.f / 3.f);
        float xnB0 = xB0 * (2.f / 3.f), xnB1 = xB1 * (2.f / 3.f), xnB2 = xB2 * (2.f / 3.f);

        // density for both samples, one LDS fetch per unit
        float spA = bd2c, spB = bd2c;
#pragma unroll 8
        for (int u = 0; u < 64; ++u) {
            float4 q = qd4[u];
            float w2 = wd2s[u];
            float hA = fmaf(xnA0, q.x, fmaf(xnA1, q.y, fmaf(xnA2, q.z, q.w)));
            float hB = fmaf(xnB0, q.x, fmaf(xnB1, q.y, fmaf(xnB2, q.z, q.w)));
            spA = fmaf(fmaxf(hA, 0.f), w2, spA);
            spB = fmaf(fmaxf(hB, 0.f), w2, spB);
        }
        float sigA = inA ? softplus_f(spA) : 0.f;
        float sigB = inB ? softplus_f(spB) : 0.f;

        float zAn = __fadd_rn(tm, __fmul_rn((float)(iA + 1), STEPF));
        float zBn = __fadd_rn(tm, __fmul_rn((float)(iB + 1), STEPF));
        float distA = __fsub_rn(zAn, zA);   // iA<=63 < 172 always
        float distB = __fsub_rn(zBn, zB);   // iB<=127 < 172 always
        float alA = 1.f - __expf(-sigA * distA * 25.f);
        float alB = 1.f - __expf(-sigB * distB * 25.f);
        float fA = 1.f - alA + 1e-10f;
        float fB = 1.f - alB + 1e-10f;

        // product scans
        float pA = fA, pB = fB;
#pragma unroll
        for (int off = 1; off < 64; off <<= 1) {
            float nA = __shfl_up(pA, off, 64);
            float nB = __shfl_up(pB, off, 64);
            if (lane >= off) { pA *= nA; pB *= nB; }
        }
        float pexA = __shfl_up(pA, 1, 64);
        float pexB = __shfl_up(pB, 1, 64);
        if (lane == 0) { pexA = 1.f; pexB = 1.f; }
        float TA = Tc * pexA;
        float wA = alA * TA;
        float TcB = Tc * __shfl(pA, 63, 64);    // == original inter-chunk carry update
        float TB = TcB * pexB;
        float wB = alB * TB;

        float midA = 0.5f * __fadd_rn(zA, zAn);
        float midB = 0.5f * __fadd_rn(zB, zBn);
        float wmA = wA * midA;
        float wmB = wB * midB;

        // sum scans (both chunks)
        float swA = wA, smA = wmA, swB = wB, smB = wmB;
#pragma unroll
        for (int off = 1; off < 64; off <<= 1) {
            float n1 = __shfl_up(swA, off, 64);
            float n2 = __shfl_up(smA, off, 64);
            float n3 = __shfl_up(swB, off, 64);
            float n4 = __shfl_up(smB, off, 64);
            if (lane >= off) { swA += n1; smA += n2; swB += n3; smB += n4; }
        }
        float wexA = __shfl_up(swA, 1, 64), wmexA = __shfl_up(smA, 1, 64);
        float wexB = __shfl_up(swB, 1, 64), wmexB = __shfl_up(smB, 1, 64);
        if (lane == 0) { wexA = 0.f; wmexA = 0.f; wexB = 0.f; wmexB = 0.f; }

        // chunk A loss/depth (Wcar=0, WMc=0: x+0 == x exactly)
        aLb += wmA * (Wcar + wexA) - wA * (WMc + wmexA);
        aLu = fmaf(distA * wA, wA, aLu);
        aD = fmaf(wA, zA, aD);
        float WcarB = Wcar + __shfl(swA, 63, 64);
        float WMcB = WMc + __shfl(smA, 63, 64);
        // chunk B loss/depth
        aLb += wmB * (WcarB + wexB) - wB * (WMcB + wmexB);
        aLu = fmaf(distB * wB, wB, aLu);
        aD = fmaf(wB, zB, aD);

        Tc = TcB * __shfl(pB, 63, 64);
        Wcar = WcarB + __shfl(swB, 63, 64);
        WMc = WMcB + __shfl(smB, 63, 64);

        // appearance (VMEM weights + readlane dconst), per-subchunk
        float wapA = (wA > 1e-4f) ? wA : 0.f;
        float wapB = (wB > 1e-4f) ? wB : 0.f;
        if (__ballot(wapA > 0.f) != 0ull) {
            float c0 = 0.f, c1 = 0.f, c2 = 0.f;
#pragma unroll 8
            for (int u = 0; u < 64; ++u) {
                float4 A4 = apAg[u];
                float2 B2 = apBg[u];
                float dcu = RL(dcr, u);
                float h = fmaf(xnA0, A4.x, fmaf(xnA1, A4.y, fmaf(xnA2, A4.z, dcu)));
                h = fmaxf(h, 0.f);
                c0 = fmaf(h, A4.w, c0);
                c1 = fmaf(h, B2.x, c1);
                c2 = fmaf(h, B2.y, c2);
            }
            aR0 = fmaf(wapA, sigmoid_f(c0 + ba2c0), aR0);
            aR1 = fmaf(wapA, sigmoid_f(c1 + ba2c1), aR1);
            aR2 = fmaf(wapA, sigmoid_f(c2 + ba2c2), aR2);
            aS0 = fmaf(wapA, xnA0, aS0);
            aS1 = fmaf(wapA, xnA1, aS1);
            aS2 = fmaf(wapA, xnA2, aS2);
            aSw += wapA;
        }
        if (__ballot(wapB > 0.f) != 0ull) {
            float c0 = 0.f, c1 = 0.f, c2 = 0.f;
#pragma unroll 8
            for (int u = 0; u < 64; ++u) {
                float4 A4 = apAg[u];
                float2 B2 = apBg[u];
                float dcu = RL(dcr, u);
                float h = fmaf(xnB0, A4.x, fmaf(xnB1, A4.y, fmaf(xnB2, A4.z, dcu)));
                h = fmaxf(h, 0.f);
                c0 = fmaf(h, A4.w, c0);
                c1 = fmaf(h, B2.x, c1);
                c2 = fmaf(h, B2.y, c2);
            }
            aR0 = fmaf(wapB, sigmoid_f(c0 + ba2c0), aR0);
            aR1 = fmaf(wapB, sigmoid_f(c1 + ba2c1), aR1);
            aR2 = fmaf(wapB, sigmoid_f(c2 + ba2c2), aR2);
            aS0 = fmaf(wapB, xnB0, aS0);
            aS1 = fmaf(wapB, xnB1, aS1);
            aS2 = fmaf(wapB, xnB2, aS2);
            aSw += wapB;
        }
    }

    // =========== PASS 2: samples 128..172 (rare; only if T not collapsed) ===========
    if (Tc >= 1e-8f) {
        int i = 128 + lane;
        bool valid = i < NSAMP;
        float z = __fadd_rn(tm, __fmul_rn((float)i, STEPF));
        float x0 = __fadd_rn(o0, __fmul_rn(d0, z));
        float x1 = __fadd_rn(o1, __fmul_rn(d1, z));
        float x2 = __fadd_rn(o2, __fmul_rn(d2, z));
        bool inbox = valid && (x0 >= -1.5f) && (x0 <= 1.5f) && (x1 >= -1.5f) && (x1 <= 1.5f) &&
                     (x2 >= -1.5f) && (x2 <= 1.5f);
        if (__ballot(inbox) != 0ull) {
            float xn0 = x0 * (2.f / 3.f), xn1 = x1 * (2.f / 3.f), xn2 = x2 * (2.f / 3.f);

            float sp = bd2c;
#pragma unroll 8
            for (int u = 0; u < 64; ++u) {
                float4 q = qd4[u];
                float h = fmaf(xn0, q.x, fmaf(xn1, q.y, fmaf(xn2, q.z, q.w)));
                sp = fmaf(fmaxf(h, 0.f), wd2s[u], sp);
            }
            float sigma = inbox ? softplus_f(sp) : 0.f;

            float znext = __fadd_rn(tm, __fmul_rn((float)(i + 1), STEPF));
            float dist = (i < LASTI) ? __fsub_rn(znext, z) : 0.f;
            float alpha = 1.f - __expf(-sigma * dist * 25.f);
            float f = 1.f - alpha + 1e-10f;

            float p = f;
#pragma unroll
            for (int off = 1; off < 64; off <<= 1) {
                float n = __shfl_up(p, off, 64);
                if (lane >= off) p *= n;
            }
            float pex = __shfl_up(p, 1, 64);
            if (lane == 0) pex = 1.f;
            float T = Tc * pex;
            float w = alpha * T;

            float mid = (i < LASTI) ? 0.5f * __fadd_rn(z, znext) : zlast2;
            float wm = w * mid;

            float sw = w, swm = wm;
#pragma unroll
            for (int off = 1; off < 64; off <<= 1) {
                float n1 = __shfl_up(sw, off, 64);
                float n2 = __shfl_up(swm, off, 64);
                if (lane >= off) { sw += n1; swm += n2; }
            }
            float wex = __shfl_up(sw, 1, 64);
            float wmex = __shfl_up(swm, 1, 64);
            if (lane == 0) { wex = 0.f; wmex = 0.f; }

            aLb += wm * (Wcar + wex) - w * (WMc + wmex);
            aLu = fmaf(dist * w, w, aLu);
            aD = fmaf(w, z, aD);
            Wcar += __shfl(sw, 63, 64);
            WMc += __shfl(swm, 63, 64);

            float wapp = (w > 1e-4f) ? w : 0.f;
            if (__ballot(wapp > 0.f) != 0ull) {
                float c0 = 0.f, c1 = 0.f, c2 = 0.f;
#pragma unroll 8
                for (int u = 0; u < 64; ++u) {
                    float4 A4 = apAg[u];
                    float2 B2 = apBg[u];
                    float dcu = RL(dcr, u);
                    float h = fmaf(xn0, A4.x, fmaf(xn1, A4.y, fmaf(xn2, A4.z, dcu)));
                    h = fmaxf(h, 0.f);
                    c0 = fmaf(h, A4.w, c0);
                    c1 = fmaf(h, B2.x, c1);
                    c2 = fmaf(h, B2.y, c2);
                }
                aR0 = fmaf(wapp, sigmoid_f(c0 + ba2c0), aR0);
                aR1 = fmaf(wapp, sigmoid_f(c1 + ba2c1), aR1);
                aR2 = fmaf(wapp, sigmoid_f(c2 + ba2c2), aR2);
                aS0 = fmaf(wapp, xn0, aS0);
                aS1 = fmaf(wapp, xn1, aS1);
                aS2 = fmaf(wapp, xn2, aS2);
                aSw += wapp;
            }
        }
    }

    // wave reductions
    aR0 = wave_sum64(aR0); aR1 = wave_sum64(aR1); aR2 = wave_sum64(aR2);
    aS0 = wave_sum64(aS0); aS1 = wave_sum64(aS1); aS2 = wave_sum64(aS2);
    aSw = wave_sum64(aSw);
    aD = wave_sum64(aD);
    aLu = wave_sum64(aLu);
    aLb = wave_sum64(aLb);

    float opac = Wcar;
    int wb = *whitebg_p;
    float bg = wb ? (1.f - opac) : 0.f;

    float* out_rgb = out;
    float* out_sem = out + 24576;
    float* out_inst = out + 188416;
    float* out_dep = out + 319488;

    if (lane < 3) {
        float rv = (lane == 0 ? aR0 : (lane == 1 ? aR1 : aR2)) + bg;
        rv = fminf(fmaxf(rv, 0.f), 1.f);
        out_rgb[r * 3 + lane] = rv;
    }
    if (lane < 20) {
        float sv = aS0 * prep[960 + lane] + aS1 * prep[980 + lane] + aS2 * prep[1000 + lane] +
                   aSw * prep[1020 + lane];
        out_sem[r * 20 + lane] = sv;
    }
    if (lane < 16) {
        float iv = aS0 * prep[1040 + lane] + aS1 * prep[1056 + lane] + aS2 * prep[1072 + lane];
        out_inst[r * 16 + lane] = iv;
    }
    if (lane == 0) {
        out_dep[r] = aD;
        wsdist[r] = aLu * (1.f / 3.f) + 2.f * aLb;
    }
}

__global__ void reduce_dist_kernel(const float* __restrict__ ws, float* __restrict__ out) {
    __shared__ float sm[256];
    int t = threadIdx.x;
    float a = 0.f;
    const float4* w4 = (const float4*)ws;
    for (int i = t; i < NRAYS / 4; i += 256) {
        float4 v = w4[i];
        a += (v.x + v.y) + (v.z + v.w);
    }
    sm[t] = a;
    __syncthreads();
    for (int st = 128; st > 0; st >>= 1) {
        if (t < st) sm[t] += sm[t + st];
        __syncthreads();
    }
    if (t == 0) out[0] = sm[0] * (1.f / (float)NRAYS);
}

extern "C" void kernel_launch(void* const* d_in, const int* in_sizes, int n_in,
                              void* d_out, int out_size, void* d_ws, size_t ws_size,
                              hipStream_t stream) {
    const float* rays = (const float*)d_in[0];
    const float* Wd1  = (const float*)d_in[1];
    const float* bd1  = (const float*)d_in[2];
    const float* Wd2  = (const float*)d_in[3];
    const float* bd2  = (const float*)d_in[4];
    const float* Wapp = (const float*)d_in[5];
    const float* Wa1  = (const float*)d_in[6];
    const float* ba1  = (const float*)d_in[7];
    const float* Wa2  = (const float*)d_in[8];
    const float* ba2  = (const float*)d_in[9];
    const float* Wsf  = (const float*)d_in[10];
    const float* Wsm  = (const float*)d_in[11];
    const float* bsm  = (const float*)d_in[12];
    const float* Wi   = (const float*)d_in[13];
    const int* wb     = (const int*)d_in[15];

    float* out = (float*)d_out;
    float* prep = (float*)d_ws;
    float* wsd  = prep + 2048;

    prep_kernel<<<1, 256, 0, stream>>>(Wd1, bd1, Wd2, bd2, Wapp, Wa1, ba1, Wa2, ba2,
                                       Wsf, Wsm, bsm, Wi, prep);
    render_kernel<<<NBLK, 256, 0, stream>>>(rays, prep, wb, out, wsd);
    reduce_dist_kernel<<<1, 256, 0, stream>>>(wsd, out + 327680);
}

// Round 11
// 34.453 us; speedup vs baseline: 2.1674x; 1.0574x over previous
//
#include <hip/hip_runtime.h>

#define NRAYS 8192
#define NSAMP 173
#define LASTI 172
#define NBLK  (NRAYS / 4)

__device__ __forceinline__ float RL(float x, int u) {
    return __int_as_float(__builtin_amdgcn_readlane(__float_as_int(x), u));
}

// DPP helper: result = (lane enabled by masks && src in range) ? src[dpp] : old
template <int CTRL, int RM, bool BC>
__device__ __forceinline__ float updpp(float old, float x) {
    return __int_as_float(__builtin_amdgcn_update_dpp(
        __float_as_int(old), __float_as_int(x), CTRL, RM, 0xf, BC));
}

// wave64 inclusive add-scan: row_shr 1/2/4/8 (OOB->0), bcast15 (rows1,3), bcast31 (rows2,3)
__device__ __forceinline__ float scan_add64(float x) {
    x += updpp<0x111, 0xf, true>(0.f, x);
    x += updpp<0x112, 0xf, true>(0.f, x);
    x += updpp<0x114, 0xf, true>(0.f, x);
    x += updpp<0x118, 0xf, true>(0.f, x);
    x += updpp<0x142, 0xa, true>(0.f, x);
    x += updpp<0x143, 0xc, true>(0.f, x);
    return x;
}

// wave64 inclusive mul-scan: keep-old=1.0 for OOB/masked lanes
__device__ __forceinline__ float scan_mul64(float x) {
    x *= updpp<0x111, 0xf, false>(1.f, x);
    x *= updpp<0x112, 0xf, false>(1.f, x);
    x *= updpp<0x114, 0xf, false>(1.f, x);
    x *= updpp<0x118, 0xf, false>(1.f, x);
    x *= updpp<0x142, 0xa, false>(1.f, x);
    x *= updpp<0x143, 0xc, false>(1.f, x);
    return x;
}

__device__ __forceinline__ float wave_sum64(float v) {
    return RL(scan_add64(v), 63);
}

__device__ __forceinline__ float softplus_f(float x) {
    if (x > 15.f) return x;
    return __logf(1.f + __expf(x));
}
__device__ __forceinline__ float sigmoid_f(float x) {
    return 1.f / (1.f + __expf(-x));
}

// ---- prep layout (float offsets into d_ws) ----
//   0    qd4[64]   float4 (Wd1 cols, bd1)
//   256  wd2[64]
//   320  dpack[64] float4 (Wa1 rows 27..29, ba1)
//   576  apA[64]   float4 (wac0, wac1, wac2, Wa2[u][0])   wac = Wapp @ Wa1[:27]
//   832  apB[64]   float2 (Wa2[u][1], Wa2[u][2])
//   960  wscs[60]  1020 bsm[20]  1040 wi[48]  1088 bd2  1089 ba2[3]
__global__ void prep_kernel(
    const float* __restrict__ Wd1, const float* __restrict__ bd1,
    const float* __restrict__ Wd2, const float* __restrict__ bd2,
    const float* __restrict__ Wapp, const float* __restrict__ Wa1,
    const float* __restrict__ ba1, const float* __restrict__ Wa2,
    const float* __restrict__ ba2, const float* __restrict__ Wsf,
    const float* __restrict__ Wsm, const float* __restrict__ bsm,
    const float* __restrict__ Wi, float* __restrict__ prep)
{
    const int t = threadIdx.x;
    if (t < 64) {
        ((float4*)prep)[t] = make_float4(Wd1[t], Wd1[64 + t], Wd1[128 + t], bd1[t]);
        prep[256 + t] = Wd2[t];
        ((float4*)(prep + 320))[t] =
            make_float4(Wa1[27 * 64 + t], Wa1[28 * 64 + t], Wa1[29 * 64 + t], ba1[t]);
    } else if (t < 128) {
        int u = t - 64;
        prep[832 + 2 * u]     = Wa2[3 * u + 1];
        prep[832 + 2 * u + 1] = Wa2[3 * u + 2];
    } else if (t < 192) {
        int u = t - 128;
        float s0 = 0.f, s1 = 0.f, s2 = 0.f;
        for (int j = 0; j < 27; ++j) {
            float w = Wa1[j * 64 + u];
            s0 = fmaf(Wapp[j], w, s0);
            s1 = fmaf(Wapp[27 + j], w, s1);
            s2 = fmaf(Wapp[54 + j], w, s2);
        }
        ((float4*)(prep + 576))[u] = make_float4(s0, s1, s2, Wa2[3 * u]);
    } else {
        for (int job = t - 192; job < 132; job += 64) {
            if (job < 60) {
                int m = job / 20, s = job % 20;
                float a = 0.f;
                for (int k = 0; k < 32; ++k) a = fmaf(Wsf[m * 32 + k], Wsm[k * 20 + s], a);
                prep[960 + job] = a;
            } else if (job < 80) {
                prep[1020 + (job - 60)] = bsm[job - 60];
            } else if (job < 128) {
                prep[1040 + (job - 80)] = Wi[job - 80];
            } else if (job == 128) {
                prep[1088] = bd2[0];
            } else {
                prep[1089 + (job - 129)] = ba2[job - 129];
            }
        }
    }
}

__launch_bounds__(256, 4)
__global__ void render_kernel(
    const float* __restrict__ rays,
    const float* __restrict__ prep,
    const int* __restrict__ whitebg_p,
    float* __restrict__ out,
    float* __restrict__ wsdist)
{
    // density weights via LDS (ds pipe); appearance via VMEM (TA pipe)
    __shared__ float4 qd4[64];
    __shared__ float  wd2s[64];

    const int t = threadIdx.x;
    const int wid = t >> 6, lane = t & 63;
    const int r = blockIdx.x * 4 + wid;

    if (t < 64) {
        qd4[t] = ((const float4*)prep)[t];
        wd2s[t] = prep[256 + t];
    }

    const float4* __restrict__ apAg = (const float4*)(prep + 576);
    const float2* __restrict__ apBg = (const float2*)(prep + 832);

    // ray (wave-uniform)
    const float o0 = rays[r * 6 + 0], o1 = rays[r * 6 + 1], o2 = rays[r * 6 + 2];
    const float d0 = rays[r * 6 + 3], d1 = rays[r * 6 + 4], d2 = rays[r * 6 + 5];

    // t_min -- replicate numpy f32 rounding exactly (knife-edge: sample 0 on box face)
    float tm;
    {
        float v0 = (d0 == 0.f) ? 1e-6f : d0;
        float v1 = (d1 == 0.f) ? 1e-6f : d1;
        float v2 = (d2 == 0.f) ? 1e-6f : d2;
        float a0 = __fdiv_rn(__fsub_rn(1.5f, o0), v0), b0 = __fdiv_rn(__fsub_rn(-1.5f, o0), v0);
        float a1 = __fdiv_rn(__fsub_rn(1.5f, o1), v1), b1 = __fdiv_rn(__fsub_rn(-1.5f, o1), v1);
        float a2 = __fdiv_rn(__fsub_rn(1.5f, o2), v2), b2 = __fdiv_rn(__fsub_rn(-1.5f, o2), v2);
        float m0 = fminf(a0, b0), m1 = fminf(a1, b1), m2 = fminf(a2, b2);
        tm = fmaxf(fmaxf(m0, m1), m2);
        tm = fminf(fmaxf(tm, 0.05f), 6.0f);
    }

    // per-ray appearance dconst for unit==lane (lane-distributed; broadcast via readlane)
    float dcr;
    {
        float4 dp = ((const float4*)(prep + 320))[lane];
        dcr = fmaf(d2, dp.z, fmaf(d1, dp.y, fmaf(d0, dp.x, dp.w)));
    }
    __syncthreads();

    const float bd2c = prep[1088];
    const float ba2c0 = prep[1089], ba2c1 = prep[1090], ba2c2 = prep[1091];

    const float STEPF = (float)(3.0 / 299.001 * 3.0);
    const float zlast2 = __fadd_rn(tm, __fmul_rn(171.f, STEPF));

    float aR0 = 0.f, aR1 = 0.f, aR2 = 0.f;
    float aS0 = 0.f, aS1 = 0.f, aS2 = 0.f;
    float aSw = 0.f;
    float aD = 0.f, aLu = 0.f, aLb = 0.f;
    float Tc = 1.f, Wcar = 0.f, WMc = 0.f;

    // =========== PASS 1: samples 0..127, two per lane, ONE weight fetch ===========
    {
        const int iA = lane, iB = 64 + lane;
        float zA = __fadd_rn(tm, __fmul_rn((float)iA, STEPF));
        float zB = __fadd_rn(tm, __fmul_rn((float)iB, STEPF));
        float xA0 = __fadd_rn(o0, __fmul_rn(d0, zA));
        float xA1 = __fadd_rn(o1, __fmul_rn(d1, zA));
        float xA2 = __fadd_rn(o2, __fmul_rn(d2, zA));
        float xB0 = __fadd_rn(o0, __fmul_rn(d0, zB));
        float xB1 = __fadd_rn(o1, __fmul_rn(d1, zB));
        float xB2 = __fadd_rn(o2, __fmul_rn(d2, zB));
        bool inA = (xA0 >= -1.5f) && (xA0 <= 1.5f) && (xA1 >= -1.5f) && (xA1 <= 1.5f) &&
                   (xA2 >= -1.5f) && (xA2 <= 1.5f);
        bool inB = (xB0 >= -1.5f) && (xB0 <= 1.5f) && (xB1 >= -1.5f) && (xB1 <= 1.5f) &&
                   (xB2 >= -1.5f) && (xB2 <= 1.5f);

        float xnA0 = xA0 * (2.f / 3.f), xnA1 = xA1 * (2.f / 3.f), xnA2 = xA2 * (2.f / 3.f);
        float xnB0 = xB0 * (2.f / 3.f), xnB1 = xB1 * (2.f / 3.f), xnB2 = xB2 * (2.f / 3.f);

        // density for both samples, one LDS fetch per unit
        float spA = bd2c, spB = bd2c;
#pragma unroll 8
        for (int u = 0; u < 64; ++u) {
            float4 q = qd4[u];
            float w2 = wd2s[u];
            float hA = fmaf(xnA0, q.x, fmaf(xnA1, q.y, fmaf(xnA2, q.z, q.w)));
            float hB = fmaf(xnB0, q.x, fmaf(xnB1, q.y, fmaf(xnB2, q.z, q.w)));
            spA = fmaf(fmaxf(hA, 0.f), w2, spA);
            spB = fmaf(fmaxf(hB, 0.f), w2, spB);
        }
        float sigA = inA ? softplus_f(spA) : 0.f;
        float sigB = inB ? softplus_f(spB) : 0.f;

        float zAn = __fadd_rn(tm, __fmul_rn((float)(iA + 1), STEPF));
        float zBn = __fadd_rn(tm, __fmul_rn((float)(iB + 1), STEPF));
        float distA = __fsub_rn(zAn, zA);
        float distB = __fsub_rn(zBn, zB);
        float alA = 1.f - __expf(-sigA * distA * 25.f);
        float alB = 1.f - __expf(-sigB * distB * 25.f);
        float fA = 1.f - alA + 1e-10f;
        float fB = 1.f - alB + 1e-10f;

        // product scans (DPP, VALU pipe, no exec churn / lgkm waits)
        float pA = scan_mul64(fA);
        float pB = scan_mul64(fB);
        float pexA = updpp<0x138, 0xf, false>(1.f, pA);  // wave_shr1, lane0 -> 1
        float pexB = updpp<0x138, 0xf, false>(1.f, pB);
        float TA = Tc * pexA;
        float wA = alA * TA;
        float TcB = Tc * RL(pA, 63);
        float TB = TcB * pexB;
        float wB = alB * TB;

        float midA = 0.5f * __fadd_rn(zA, zAn);
        float midB = 0.5f * __fadd_rn(zB, zBn);
        float wmA = wA * midA;
        float wmB = wB * midB;

        // sum scans (DPP)
        float swA = scan_add64(wA), smA = scan_add64(wmA);
        float swB = scan_add64(wB), smB = scan_add64(wmB);
        float wexA = updpp<0x138, 0xf, true>(0.f, swA);
        float wmexA = updpp<0x138, 0xf, true>(0.f, smA);
        float wexB = updpp<0x138, 0xf, true>(0.f, swB);
        float wmexB = updpp<0x138, 0xf, true>(0.f, smB);

        aLb += wmA * (Wcar + wexA) - wA * (WMc + wmexA);
        aLu = fmaf(distA * wA, wA, aLu);
        aD = fmaf(wA, zA, aD);
        float WcarB = Wcar + RL(swA, 63);
        float WMcB = WMc + RL(smA, 63);
        aLb += wmB * (WcarB + wexB) - wB * (WMcB + wmexB);
        aLu = fmaf(distB * wB, wB, aLu);
        aD = fmaf(wB, zB, aD);

        Tc = TcB * RL(pB, 63);
        Wcar = WcarB + RL(swB, 63);
        WMc = WMcB + RL(smB, 63);

        // appearance (VMEM weights + readlane dconst), per-subchunk
        float wapA = (wA > 1e-4f) ? wA : 0.f;
        float wapB = (wB > 1e-4f) ? wB : 0.f;
        if (__ballot(wapA > 0.f) != 0ull) {
            float c0 = 0.f, c1 = 0.f, c2 = 0.f;
#pragma unroll 8
            for (int u = 0; u < 64; ++u) {
                float4 A4 = apAg[u];
                float2 B2 = apBg[u];
                float dcu = RL(dcr, u);
                float h = fmaf(xnA0, A4.x, fmaf(xnA1, A4.y, fmaf(xnA2, A4.z, dcu)));
                h = fmaxf(h, 0.f);
                c0 = fmaf(h, A4.w, c0);
                c1 = fmaf(h, B2.x, c1);
                c2 = fmaf(h, B2.y, c2);
            }
            aR0 = fmaf(wapA, sigmoid_f(c0 + ba2c0), aR0);
            aR1 = fmaf(wapA, sigmoid_f(c1 + ba2c1), aR1);
            aR2 = fmaf(wapA, sigmoid_f(c2 + ba2c2), aR2);
            aS0 = fmaf(wapA, xnA0, aS0);
            aS1 = fmaf(wapA, xnA1, aS1);
            aS2 = fmaf(wapA, xnA2, aS2);
            aSw += wapA;
        }
        if (__ballot(wapB > 0.f) != 0ull) {
            float c0 = 0.f, c1 = 0.f, c2 = 0.f;
#pragma unroll 8
            for (int u = 0; u < 64; ++u) {
                float4 A4 = apAg[u];
                float2 B2 = apBg[u];
                float dcu = RL(dcr, u);
                float h = fmaf(xnB0, A4.x, fmaf(xnB1, A4.y, fmaf(xnB2, A4.z, dcu)));
                h = fmaxf(h, 0.f);
                c0 = fmaf(h, A4.w, c0);
                c1 = fmaf(h, B2.x, c1);
                c2 = fmaf(h, B2.y, c2);
            }
            aR0 = fmaf(wapB, sigmoid_f(c0 + ba2c0), aR0);
            aR1 = fmaf(wapB, sigmoid_f(c1 + ba2c1), aR1);
            aR2 = fmaf(wapB, sigmoid_f(c2 + ba2c2), aR2);
            aS0 = fmaf(wapB, xnB0, aS0);
            aS1 = fmaf(wapB, xnB1, aS1);
            aS2 = fmaf(wapB, xnB2, aS2);
            aSw += wapB;
        }
    }

    // =========== PASS 2: samples 128..172 (rare; only if T not collapsed) ===========
    if (Tc >= 1e-8f) {
        int i = 128 + lane;
        bool valid = i < NSAMP;
        float z = __fadd_rn(tm, __fmul_rn((float)i, STEPF));
        float x0 = __fadd_rn(o0, __fmul_rn(d0, z));
        float x1 = __fadd_rn(o1, __fmul_rn(d1, z));
        float x2 = __fadd_rn(o2, __fmul_rn(d2, z));
        bool inbox = valid && (x0 >= -1.5f) && (x0 <= 1.5f) && (x1 >= -1.5f) && (x1 <= 1.5f) &&
                     (x2 >= -1.5f) && (x2 <= 1.5f);
        if (__ballot(inbox) != 0ull) {
            float xn0 = x0 * (2.f / 3.f), xn1 = x1 * (2.f / 3.f), xn2 = x2 * (2.f / 3.f);

            float sp = bd2c;
#pragma unroll 8
            for (int u = 0; u < 64; ++u) {
                float4 q = qd4[u];
                float h = fmaf(xn0, q.x, fmaf(xn1, q.y, fmaf(xn2, q.z, q.w)));
                sp = fmaf(fmaxf(h, 0.f), wd2s[u], sp);
            }
            float sigma = inbox ? softplus_f(sp) : 0.f;

            float znext = __fadd_rn(tm, __fmul_rn((float)(i + 1), STEPF));
            float dist = (i < LASTI) ? __fsub_rn(znext, z) : 0.f;
            float alpha = 1.f - __expf(-sigma * dist * 25.f);
            float f = 1.f - alpha + 1e-10f;

            float p = scan_mul64(f);
            float pex = updpp<0x138, 0xf, false>(1.f, p);
            float T = Tc * pex;
            float w = alpha * T;

            float mid = (i < LASTI) ? 0.5f * __fadd_rn(z, znext) : zlast2;
            float wm = w * mid;

            float sw = scan_add64(w);
            float swm = scan_add64(wm);
            float wex = updpp<0x138, 0xf, true>(0.f, sw);
            float wmex = updpp<0x138, 0xf, true>(0.f, swm);

            aLb += wm * (Wcar + wex) - w * (WMc + wmex);
            aLu = fmaf(dist * w, w, aLu);
            aD = fmaf(w, z, aD);
            Wcar += RL(sw, 63);
            WMc += RL(swm, 63);

            float wapp = (w > 1e-4f) ? w : 0.f;
            if (__ballot(wapp > 0.f) != 0ull) {
                float c0 = 0.f, c1 = 0.f, c2 = 0.f;
#pragma unroll 8
                for (int u = 0; u < 64; ++u) {
                    float4 A4 = apAg[u];
                    float2 B2 = apBg[u];
                    float dcu = RL(dcr, u);
                    float h = fmaf(xn0, A4.x, fmaf(xn1, A4.y, fmaf(xn2, A4.z, dcu)));
                    h = fmaxf(h, 0.f);
                    c0 = fmaf(h, A4.w, c0);
                    c1 = fmaf(h, B2.x, c1);
                    c2 = fmaf(h, B2.y, c2);
                }
                aR0 = fmaf(wapp, sigmoid_f(c0 + ba2c0), aR0);
                aR1 = fmaf(wapp, sigmoid_f(c1 + ba2c1), aR1);
                aR2 = fmaf(wapp, sigmoid_f(c2 + ba2c2), aR2);
                aS0 = fmaf(wapp, xn0, aS0);
                aS1 = fmaf(wapp, xn1, aS1);
                aS2 = fmaf(wapp, xn2, aS2);
                aSw += wapp;
            }
        }
    }

    // wave reductions (DPP scan + readlane)
    aR0 = wave_sum64(aR0); aR1 = wave_sum64(aR1); aR2 = wave_sum64(aR2);
    aS0 = wave_sum64(aS0); aS1 = wave_sum64(aS1); aS2 = wave_sum64(aS2);
    aSw = wave_sum64(aSw);
    aD = wave_sum64(aD);
    aLu = wave_sum64(aLu);
    aLb = wave_sum64(aLb);

    float opac = Wcar;
    int wb = *whitebg_p;
    float bg = wb ? (1.f - opac) : 0.f;

    float* out_rgb = out;
    float* out_sem = out + 24576;
    float* out_inst = out + 188416;
    float* out_dep = out + 319488;

    if (lane < 3) {
        float rv = (lane == 0 ? aR0 : (lane == 1 ? aR1 : aR2)) + bg;
        rv = fminf(fmaxf(rv, 0.f), 1.f);
        out_rgb[r * 3 + lane] = rv;
    }
    if (lane < 20) {
        float sv = aS0 * prep[960 + lane] + aS1 * prep[980 + lane] + aS2 * prep[1000 + lane] +
                   aSw * prep[1020 + lane];
        out_sem[r * 20 + lane] = sv;
    }
    if (lane < 16) {
        float iv = aS0 * prep[1040 + lane] + aS1 * prep[1056 + lane] + aS2 * prep[1072 + lane];
        out_inst[r * 16 + lane] = iv;
    }
    if (lane == 0) {
        out_dep[r] = aD;
        wsdist[r] = aLu * (1.f / 3.f) + 2.f * aLb;
    }
}

__global__ void reduce_dist_kernel(const float* __restrict__ ws, float* __restrict__ out) {
    __shared__ float sm[256];
    int t = threadIdx.x;
    float a = 0.f;
    const float4* w4 = (const float4*)ws;
    for (int i = t; i < NRAYS / 4; i += 256) {
        float4 v = w4[i];
        a += (v.x + v.y) + (v.z + v.w);
    }
    sm[t] = a;
    __syncthreads();
    for (int st = 128; st > 0; st >>= 1) {
        if (t < st) sm[t] += sm[t + st];
        __syncthreads();
    }
    if (t == 0) out[0] = sm[0] * (1.f / (float)NRAYS);
}

extern "C" void kernel_launch(void* const* d_in, const int* in_sizes, int n_in,
                              void* d_out, int out_size, void* d_ws, size_t ws_size,
                              hipStream_t stream) {
    const float* rays = (const float*)d_in[0];
    const float* Wd1  = (const float*)d_in[1];
    const float* bd1  = (const float*)d_in[2];
    const float* Wd2  = (const float*)d_in[3];
    const float* bd2  = (const float*)d_in[4];
    const float* Wapp = (const float*)d_in[5];
    const float* Wa1  = (const float*)d_in[6];
    const float* ba1  = (const float*)d_in[7];
    const float* Wa2  = (const float*)d_in[8];
    const float* ba2  = (const float*)d_in[9];
    const float* Wsf  = (const float*)d_in[10];
    const float* Wsm  = (const float*)d_in[11];
    const float* bsm  = (const float*)d_in[12];
    const float* Wi   = (const float*)d_in[13];
    const int* wb     = (const int*)d_in[15];

    float* out = (float*)d_out;
    float* prep = (float*)d_ws;
    float* wsd  = prep + 2048;

    prep_kernel<<<1, 256, 0, stream>>>(Wd1, bd1, Wd2, bd2, Wapp, Wa1, ba1, Wa2, ba2,
                                       Wsf, Wsm, bsm, Wi, prep);
    render_kernel<<<NBLK, 256, 0, stream>>>(rays, prep, wb, out, wsd);
    reduce_dist_kernel<<<1, 256, 0, stream>>>(wsd, out + 327680);
}

// Round 12
// 31.826 us; speedup vs baseline: 2.3463x; 1.0825x over previous
//
#include <hip/hip_runtime.h>

#define NRAYS 8192
#define NSAMP 173
#define LASTI 172
#define NBLK  (NRAYS / 4)

__device__ __forceinline__ float RL(float x, int u) {
    return __int_as_float(__builtin_amdgcn_readlane(__float_as_int(x), u));
}

// DPP helper: result = (lane enabled by masks && src in range) ? src[dpp] : old
template <int CTRL, int RM, bool BC>
__device__ __forceinline__ float updpp(float old, float x) {
    return __int_as_float(__builtin_amdgcn_update_dpp(
        __float_as_int(old), __float_as_int(x), CTRL, RM, 0xf, BC));
}

// wave64 inclusive add-scan: row_shr 1/2/4/8 (OOB->0), bcast15 (rows1,3), bcast31 (rows2,3)
__device__ __forceinline__ float scan_add64(float x) {
    x += updpp<0x111, 0xf, true>(0.f, x);
    x += updpp<0x112, 0xf, true>(0.f, x);
    x += updpp<0x114, 0xf, true>(0.f, x);
    x += updpp<0x118, 0xf, true>(0.f, x);
    x += updpp<0x142, 0xa, true>(0.f, x);
    x += updpp<0x143, 0xc, true>(0.f, x);
    return x;
}

// wave64 inclusive mul-scan: keep-old=1.0 for OOB/masked lanes
__device__ __forceinline__ float scan_mul64(float x) {
    x *= updpp<0x111, 0xf, false>(1.f, x);
    x *= updpp<0x112, 0xf, false>(1.f, x);
    x *= updpp<0x114, 0xf, false>(1.f, x);
    x *= updpp<0x118, 0xf, false>(1.f, x);
    x *= updpp<0x142, 0xa, false>(1.f, x);
    x *= updpp<0x143, 0xc, false>(1.f, x);
    return x;
}

__device__ __forceinline__ float wave_sum64(float v) {
    return RL(scan_add64(v), 63);
}

__device__ __forceinline__ float softplus_f(float x) {
    if (x > 15.f) return x;
    return __logf(1.f + __expf(x));
}
__device__ __forceinline__ float sigmoid_f(float x) {
    return 1.f / (1.f + __expf(-x));
}

__launch_bounds__(256, 4)
__global__ void render_kernel(
    const float* __restrict__ rays,
    const float* __restrict__ Wd1, const float* __restrict__ bd1,
    const float* __restrict__ Wd2, const float* __restrict__ bd2,
    const float* __restrict__ Wapp, const float* __restrict__ Wa1,
    const float* __restrict__ ba1, const float* __restrict__ Wa2,
    const float* __restrict__ ba2, const float* __restrict__ Wsf,
    const float* __restrict__ Wsm, const float* __restrict__ bsm,
    const float* __restrict__ Wi,
    const int* __restrict__ whitebg_p,
    float* __restrict__ out,
    float* __restrict__ wsdist)
{
    // per-block folded weight tables in LDS (broadcast reads, no conflicts)
    __shared__ float4 qd4[64];   // Wd1 cols + bd1
    __shared__ float  wd2s[64];  // Wd2
    __shared__ float4 apAs[64];  // (wac0, wac1, wac2, Wa2[u][0]);  wac = Wapp @ Wa1[:27]
    __shared__ float2 apBs[64];  // (Wa2[u][1], Wa2[u][2])
    __shared__ float  wscs[60];  // (Wsf @ Wsm)[m*20+s]
    __shared__ float  bsmS[20];

    const int t = threadIdx.x;
    const int wid = t >> 6, lane = t & 63;
    const int r = blockIdx.x * 4 + wid;

    // ---- preamble: fold tables (replaces separate prep kernel; ~0.2us, L2-hot) ----
    if (t < 64) {
        qd4[t] = make_float4(Wd1[t], Wd1[64 + t], Wd1[128 + t], bd1[t]);
        wd2s[t] = Wd2[t];
    } else if (t < 128) {
        int u = t - 64;
        apBs[u] = make_float2(Wa2[3 * u + 1], Wa2[3 * u + 2]);
    } else if (t < 192) {
        int u = t - 128;
        float s0 = 0.f, s1 = 0.f, s2 = 0.f;
        for (int j = 0; j < 27; ++j) {
            float w = Wa1[j * 64 + u];
            s0 = fmaf(Wapp[j], w, s0);
            s1 = fmaf(Wapp[27 + j], w, s1);
            s2 = fmaf(Wapp[54 + j], w, s2);
        }
        apAs[u] = make_float4(s0, s1, s2, Wa2[3 * u]);
    } else {
        for (int job = t - 192; job < 80; job += 64) {
            if (job < 60) {
                int m = job / 20, s = job % 20;
                float a = 0.f;
                for (int k = 0; k < 32; ++k) a = fmaf(Wsf[m * 32 + k], Wsm[k * 20 + s], a);
                wscs[job] = a;
            } else {
                bsmS[job - 60] = bsm[job - 60];
            }
        }
    }

    // ray (wave-uniform)
    const float o0 = rays[r * 6 + 0], o1 = rays[r * 6 + 1], o2 = rays[r * 6 + 2];
    const float d0 = rays[r * 6 + 3], d1 = rays[r * 6 + 4], d2 = rays[r * 6 + 5];

    // t_min -- replicate numpy f32 rounding exactly (knife-edge: sample 0 on box face)
    float tm;
    {
        float v0 = (d0 == 0.f) ? 1e-6f : d0;
        float v1 = (d1 == 0.f) ? 1e-6f : d1;
        float v2 = (d2 == 0.f) ? 1e-6f : d2;
        float a0 = __fdiv_rn(__fsub_rn(1.5f, o0), v0), b0 = __fdiv_rn(__fsub_rn(-1.5f, o0), v0);
        float a1 = __fdiv_rn(__fsub_rn(1.5f, o1), v1), b1 = __fdiv_rn(__fsub_rn(-1.5f, o1), v1);
        float a2 = __fdiv_rn(__fsub_rn(1.5f, o2), v2), b2 = __fdiv_rn(__fsub_rn(-1.5f, o2), v2);
        float m0 = fminf(a0, b0), m1 = fminf(a1, b1), m2 = fminf(a2, b2);
        tm = fmaxf(fmaxf(m0, m1), m2);
        tm = fminf(fmaxf(tm, 0.05f), 6.0f);
    }

    // per-ray appearance dconst for unit==lane (lane-distributed; broadcast via readlane)
    float dcr;
    {
        float b = ba1[lane];
        b = fmaf(d0, Wa1[27 * 64 + lane], b);
        b = fmaf(d1, Wa1[28 * 64 + lane], b);
        b = fmaf(d2, Wa1[29 * 64 + lane], b);
        dcr = b;
    }

    const float bd2c = bd2[0];
    const float ba2c0 = ba2[0], ba2c1 = ba2[1], ba2c2 = ba2[2];

    __syncthreads();

    const float STEPF = (float)(3.0 / 299.001 * 3.0);
    const float zlast2 = __fadd_rn(tm, __fmul_rn(171.f, STEPF));

    float aR0 = 0.f, aR1 = 0.f, aR2 = 0.f;
    float aS0 = 0.f, aS1 = 0.f, aS2 = 0.f;
    float aSw = 0.f;
    float aD = 0.f, aLu = 0.f, aLb = 0.f;
    float Tc = 1.f, Wcar = 0.f, WMc = 0.f;

    // =========== PASS 1: samples 0..127, two per lane, ONE weight fetch ===========
    {
        const int iA = lane, iB = 64 + lane;
        float zA = __fadd_rn(tm, __fmul_rn((float)iA, STEPF));
        float zB = __fadd_rn(tm, __fmul_rn((float)iB, STEPF));
        float xA0 = __fadd_rn(o0, __fmul_rn(d0, zA));
        float xA1 = __fadd_rn(o1, __fmul_rn(d1, zA));
        float xA2 = __fadd_rn(o2, __fmul_rn(d2, zA));
        float xB0 = __fadd_rn(o0, __fmul_rn(d0, zB));
        float xB1 = __fadd_rn(o1, __fmul_rn(d1, zB));
        float xB2 = __fadd_rn(o2, __fmul_rn(d2, zB));
        bool inA = (xA0 >= -1.5f) && (xA0 <= 1.5f) && (xA1 >= -1.5f) && (xA1 <= 1.5f) &&
                   (xA2 >= -1.5f) && (xA2 <= 1.5f);
        bool inB = (xB0 >= -1.5f) && (xB0 <= 1.5f) && (xB1 >= -1.5f) && (xB1 <= 1.5f) &&
                   (xB2 >= -1.5f) && (xB2 <= 1.5f);

        float xnA0 = xA0 * (2.f / 3.f), xnA1 = xA1 * (2.f / 3.f), xnA2 = xA2 * (2.f / 3.f);
        float xnB0 = xB0 * (2.f / 3.f), xnB1 = xB1 * (2.f / 3.f), xnB2 = xB2 * (2.f / 3.f);

        // density for both samples, one LDS fetch per unit
        float spA = bd2c, spB = bd2c;
#pragma unroll 8
        for (int u = 0; u < 64; ++u) {
            float4 q = qd4[u];
            float w2 = wd2s[u];
            float hA = fmaf(xnA0, q.x, fmaf(xnA1, q.y, fmaf(xnA2, q.z, q.w)));
            float hB = fmaf(xnB0, q.x, fmaf(xnB1, q.y, fmaf(xnB2, q.z, q.w)));
            spA = fmaf(fmaxf(hA, 0.f), w2, spA);
            spB = fmaf(fmaxf(hB, 0.f), w2, spB);
        }
        float sigA = inA ? softplus_f(spA) : 0.f;
        float sigB = inB ? softplus_f(spB) : 0.f;

        float zAn = __fadd_rn(tm, __fmul_rn((float)(iA + 1), STEPF));
        float zBn = __fadd_rn(tm, __fmul_rn((float)(iB + 1), STEPF));
        float distA = __fsub_rn(zAn, zA);
        float distB = __fsub_rn(zBn, zB);
        float alA = 1.f - __expf(-sigA * distA * 25.f);
        float alB = 1.f - __expf(-sigB * distB * 25.f);
        float fA = 1.f - alA + 1e-10f;
        float fB = 1.f - alB + 1e-10f;

        // product scans (DPP, VALU pipe)
        float pA = scan_mul64(fA);
        float pB = scan_mul64(fB);
        float pexA = updpp<0x138, 0xf, false>(1.f, pA);  // wave_shr1, lane0 -> 1
        float pexB = updpp<0x138, 0xf, false>(1.f, pB);
        float TA = Tc * pexA;
        float wA = alA * TA;
        float TcB = Tc * RL(pA, 63);
        float TB = TcB * pexB;
        float wB = alB * TB;

        float midA = 0.5f * __fadd_rn(zA, zAn);
        float midB = 0.5f * __fadd_rn(zB, zBn);
        float wmA = wA * midA;
        float wmB = wB * midB;

        // sum scans (DPP)
        float swA = scan_add64(wA), smA = scan_add64(wmA);
        float swB = scan_add64(wB), smB = scan_add64(wmB);
        float wexA = updpp<0x138, 0xf, true>(0.f, swA);
        float wmexA = updpp<0x138, 0xf, true>(0.f, smA);
        float wexB = updpp<0x138, 0xf, true>(0.f, swB);
        float wmexB = updpp<0x138, 0xf, true>(0.f, smB);

        aLb += wmA * (Wcar + wexA) - wA * (WMc + wmexA);
        aLu = fmaf(distA * wA, wA, aLu);
        aD = fmaf(wA, zA, aD);
        float WcarB = Wcar + RL(swA, 63);
        float WMcB = WMc + RL(smA, 63);
        aLb += wmB * (WcarB + wexB) - wB * (WMcB + wmexB);
        aLu = fmaf(distB * wB, wB, aLu);
        aD = fmaf(wB, zB, aD);

        Tc = TcB * RL(pB, 63);
        Wcar = WcarB + RL(swB, 63);
        WMc = WMcB + RL(smB, 63);

        // appearance (LDS weights + readlane dconst), per-subchunk
        float wapA = (wA > 1e-4f) ? wA : 0.f;
        float wapB = (wB > 1e-4f) ? wB : 0.f;
        if (__ballot(wapA > 0.f) != 0ull) {
            float c0 = 0.f, c1 = 0.f, c2 = 0.f;
#pragma unroll 8
            for (int u = 0; u < 64; ++u) {
                float4 A4 = apAs[u];
                float2 B2 = apBs[u];
                float dcu = RL(dcr, u);
                float h = fmaf(xnA0, A4.x, fmaf(xnA1, A4.y, fmaf(xnA2, A4.z, dcu)));
                h = fmaxf(h, 0.f);
                c0 = fmaf(h, A4.w, c0);
                c1 = fmaf(h, B2.x, c1);
                c2 = fmaf(h, B2.y, c2);
            }
            aR0 = fmaf(wapA, sigmoid_f(c0 + ba2c0), aR0);
            aR1 = fmaf(wapA, sigmoid_f(c1 + ba2c1), aR1);
            aR2 = fmaf(wapA, sigmoid_f(c2 + ba2c2), aR2);
            aS0 = fmaf(wapA, xnA0, aS0);
            aS1 = fmaf(wapA, xnA1, aS1);
            aS2 = fmaf(wapA, xnA2, aS2);
            aSw += wapA;
        }
        if (__ballot(wapB > 0.f) != 0ull) {
            float c0 = 0.f, c1 = 0.f, c2 = 0.f;
#pragma unroll 8
            for (int u = 0; u < 64; ++u) {
                float4 A4 = apAs[u];
                float2 B2 = apBs[u];
                float dcu = RL(dcr, u);
                float h = fmaf(xnB0, A4.x, fmaf(xnB1, A4.y, fmaf(xnB2, A4.z, dcu)));
                h = fmaxf(h, 0.f);
                c0 = fmaf(h, A4.w, c0);
                c1 = fmaf(h, B2.x, c1);
                c2 = fmaf(h, B2.y, c2);
            }
            aR0 = fmaf(wapB, sigmoid_f(c0 + ba2c0), aR0);
            aR1 = fmaf(wapB, sigmoid_f(c1 + ba2c1), aR1);
            aR2 = fmaf(wapB, sigmoid_f(c2 + ba2c2), aR2);
            aS0 = fmaf(wapB, xnB0, aS0);
            aS1 = fmaf(wapB, xnB1, aS1);
            aS2 = fmaf(wapB, xnB2, aS2);
            aSw += wapB;
        }
    }

    // =========== PASS 2: samples 128..172 (rare; only if T not collapsed) ===========
    if (Tc >= 1e-8f) {
        int i = 128 + lane;
        bool valid = i < NSAMP;
        float z = __fadd_rn(tm, __fmul_rn((float)i, STEPF));
        float x0 = __fadd_rn(o0, __fmul_rn(d0, z));
        float x1 = __fadd_rn(o1, __fmul_rn(d1, z));
        float x2 = __fadd_rn(o2, __fmul_rn(d2, z));
        bool inbox = valid && (x0 >= -1.5f) && (x0 <= 1.5f) && (x1 >= -1.5f) && (x1 <= 1.5f) &&
                     (x2 >= -1.5f) && (x2 <= 1.5f);
        if (__ballot(inbox) != 0ull) {
            float xn0 = x0 * (2.f / 3.f), xn1 = x1 * (2.f / 3.f), xn2 = x2 * (2.f / 3.f);

            float sp = bd2c;
#pragma unroll 8
            for (int u = 0; u < 64; ++u) {
                float4 q = qd4[u];
                float h = fmaf(xn0, q.x, fmaf(xn1, q.y, fmaf(xn2, q.z, q.w)));
                sp = fmaf(fmaxf(h, 0.f), wd2s[u], sp);
            }
            float sigma = inbox ? softplus_f(sp) : 0.f;

            float znext = __fadd_rn(tm, __fmul_rn((float)(i + 1), STEPF));
            float dist = (i < LASTI) ? __fsub_rn(znext, z) : 0.f;
            float alpha = 1.f - __expf(-sigma * dist * 25.f);
            float f = 1.f - alpha + 1e-10f;

            float p = scan_mul64(f);
            float pex = updpp<0x138, 0xf, false>(1.f, p);
            float T = Tc * pex;
            float w = alpha * T;

            float mid = (i < LASTI) ? 0.5f * __fadd_rn(z, znext) : zlast2;
            float wm = w * mid;

            float sw = scan_add64(w);
            float swm = scan_add64(wm);
            float wex = updpp<0x138, 0xf, true>(0.f, sw);
            float wmex = updpp<0x138, 0xf, true>(0.f, swm);

            aLb += wm * (Wcar + wex) - w * (WMc + wmex);
            aLu = fmaf(dist * w, w, aLu);
            aD = fmaf(w, z, aD);
            Wcar += RL(sw, 63);
            WMc += RL(swm, 63);

            float wapp = (w > 1e-4f) ? w : 0.f;
            if (__ballot(wapp > 0.f) != 0ull) {
                float c0 = 0.f, c1 = 0.f, c2 = 0.f;
#pragma unroll 8
                for (int u = 0; u < 64; ++u) {
                    float4 A4 = apAs[u];
                    float2 B2 = apBs[u];
                    float dcu = RL(dcr, u);
                    float h = fmaf(xn0, A4.x, fmaf(xn1, A4.y, fmaf(xn2, A4.z, dcu)));
                    h = fmaxf(h, 0.f);
                    c0 = fmaf(h, A4.w, c0);
                    c1 = fmaf(h, B2.x, c1);
                    c2 = fmaf(h, B2.y, c2);
                }
                aR0 = fmaf(wapp, sigmoid_f(c0 + ba2c0), aR0);
                aR1 = fmaf(wapp, sigmoid_f(c1 + ba2c1), aR1);
                aR2 = fmaf(wapp, sigmoid_f(c2 + ba2c2), aR2);
                aS0 = fmaf(wapp, xn0, aS0);
                aS1 = fmaf(wapp, xn1, aS1);
                aS2 = fmaf(wapp, xn2, aS2);
                aSw += wapp;
            }
        }
    }

    // wave reductions (DPP scan + readlane)
    aR0 = wave_sum64(aR0); aR1 = wave_sum64(aR1); aR2 = wave_sum64(aR2);
    aS0 = wave_sum64(aS0); aS1 = wave_sum64(aS1); aS2 = wave_sum64(aS2);
    aSw = wave_sum64(aSw);
    aD = wave_sum64(aD);
    aLu = wave_sum64(aLu);
    aLb = wave_sum64(aLb);

    float opac = Wcar;
    int wb = *whitebg_p;
    float bg = wb ? (1.f - opac) : 0.f;

    float* out_rgb = out;
    float* out_sem = out + 24576;
    float* out_inst = out + 188416;
    float* out_dep = out + 319488;

    if (lane < 3) {
        float rv = (lane == 0 ? aR0 : (lane == 1 ? aR1 : aR2)) + bg;
        rv = fminf(fmaxf(rv, 0.f), 1.f);
        out_rgb[r * 3 + lane] = rv;
    }
    if (lane < 20) {
        float sv = aS0 * wscs[lane] + aS1 * wscs[20 + lane] + aS2 * wscs[40 + lane] +
                   aSw * bsmS[lane];
        out_sem[r * 20 + lane] = sv;
    }
    if (lane < 16) {
        float iv = aS0 * Wi[lane] + aS1 * Wi[16 + lane] + aS2 * Wi[32 + lane];
        out_inst[r * 16 + lane] = iv;
    }
    if (lane == 0) {
        out_dep[r] = aD;
        wsdist[r] = aLu * (1.f / 3.f) + 2.f * aLb;
    }
}

__global__ void reduce_dist_kernel(const float* __restrict__ ws, float* __restrict__ out) {
    __shared__ float sm[256];
    int t = threadIdx.x;
    float a = 0.f;
    const float4* w4 = (const float4*)ws;
    for (int i = t; i < NRAYS / 4; i += 256) {
        float4 v = w4[i];
        a += (v.x + v.y) + (v.z + v.w);
    }
    sm[t] = a;
    __syncthreads();
    for (int st = 128; st > 0; st >>= 1) {
        if (t < st) sm[t] += sm[t + st];
        __syncthreads();
    }
    if (t == 0) out[0] = sm[0] * (1.f / (float)NRAYS);
}

extern "C" void kernel_launch(void* const* d_in, const int* in_sizes, int n_in,
                              void* d_out, int out_size, void* d_ws, size_t ws_size,
                              hipStream_t stream) {
    const float* rays = (const float*)d_in[0];
    const float* Wd1  = (const float*)d_in[1];
    const float* bd1  = (const float*)d_in[2];
    const float* Wd2  = (const float*)d_in[3];
    const float* bd2  = (const float*)d_in[4];
    const float* Wapp = (const float*)d_in[5];
    const float* Wa1  = (const float*)d_in[6];
    const float* ba1  = (const float*)d_in[7];
    const float* Wa2  = (const float*)d_in[8];
    const float* ba2  = (const float*)d_in[9];
    const float* Wsf  = (const float*)d_in[10];
    const float* Wsm  = (const float*)d_in[11];
    const float* bsm  = (const float*)d_in[12];
    const float* Wi   = (const float*)d_in[13];
    const int* wb     = (const int*)d_in[15];

    float* out = (float*)d_out;
    float* wsd = (float*)d_ws;   // 8192 f32 per-ray dist values

    render_kernel<<<NBLK, 256, 0, stream>>>(rays, Wd1, bd1, Wd2, bd2, Wapp, Wa1, ba1,
                                            Wa2, ba2, Wsf, Wsm, bsm, Wi, wb, out, wsd);
    reduce_dist_kernel<<<1, 256, 0, stream>>>(wsd, out + 327680);
}

// Round 13
// 29.249 us; speedup vs baseline: 2.5530x; 1.0881x over previous
//
#include <hip/hip_runtime.h>

#define NRAYS 8192
#define NSAMP 173
#define LASTI 172
#define NBLK  (NRAYS / 4)

__device__ __forceinline__ float RL(float x, int u) {
    return __int_as_float(__builtin_amdgcn_readlane(__float_as_int(x), u));
}

// DPP helper: result = (lane enabled by masks && src in range) ? src[dpp] : old
template <int CTRL, int RM, bool BC>
__device__ __forceinline__ float updpp(float old, float x) {
    return __int_as_float(__builtin_amdgcn_update_dpp(
        __float_as_int(old), __float_as_int(x), CTRL, RM, 0xf, BC));
}

// wave64 inclusive add-scan
__device__ __forceinline__ float scan_add64(float x) {
    x += updpp<0x111, 0xf, true>(0.f, x);
    x += updpp<0x112, 0xf, true>(0.f, x);
    x += updpp<0x114, 0xf, true>(0.f, x);
    x += updpp<0x118, 0xf, true>(0.f, x);
    x += updpp<0x142, 0xa, true>(0.f, x);
    x += updpp<0x143, 0xc, true>(0.f, x);
    return x;
}

// wave64 inclusive mul-scan
__device__ __forceinline__ float scan_mul64(float x) {
    x *= updpp<0x111, 0xf, false>(1.f, x);
    x *= updpp<0x112, 0xf, false>(1.f, x);
    x *= updpp<0x114, 0xf, false>(1.f, x);
    x *= updpp<0x118, 0xf, false>(1.f, x);
    x *= updpp<0x142, 0xa, false>(1.f, x);
    x *= updpp<0x143, 0xc, false>(1.f, x);
    return x;
}

__device__ __forceinline__ float wave_sum64(float v) {
    return RL(scan_add64(v), 63);
}

__device__ __forceinline__ float softplus_f(float x) {
    if (x > 15.f) return x;
    return __logf(1.f + __expf(x));
}
__device__ __forceinline__ float sigmoid_f(float x) {
    return 1.f / (1.f + __expf(-x));
}

__launch_bounds__(256, 4)
__global__ void render_kernel(
    const float* __restrict__ rays,
    const float* __restrict__ Wd1, const float* __restrict__ bd1,
    const float* __restrict__ Wd2, const float* __restrict__ bd2,
    const float* __restrict__ Wapp, const float* __restrict__ Wa1,
    const float* __restrict__ ba1, const float* __restrict__ Wa2,
    const float* __restrict__ ba2, const float* __restrict__ Wsf,
    const float* __restrict__ Wsm, const float* __restrict__ bsm,
    const float* __restrict__ Wi,
    const int* __restrict__ whitebg_p,
    float* __restrict__ out,
    float* __restrict__ wsdist)
{
    // per-block folded weight tables in LDS (broadcast reads, no conflicts)
    __shared__ float4 qd4[64];   // Wd1 cols + bd1
    __shared__ float  wd2s[64];  // Wd2
    __shared__ float4 apAs[64];  // (wac0, wac1, wac2, Wa2[u][0]);  wac = Wapp @ Wa1[:27]
    __shared__ float2 apBs[64];  // (Wa2[u][1], Wa2[u][2])
    __shared__ float  wscs[60];  // (Wsf @ Wsm)[m*20+s]
    __shared__ float  bsmS[20];

    const int t = threadIdx.x;
    const int wid = t >> 6, lane = t & 63;
    const int r = blockIdx.x * 4 + wid;

    // ---- preamble: fold tables (L2-hot after first blocks) ----
    if (t < 64) {
        qd4[t] = make_float4(Wd1[t], Wd1[64 + t], Wd1[128 + t], bd1[t]);
        wd2s[t] = Wd2[t];
    } else if (t < 128) {
        int u = t - 64;
        apBs[u] = make_float2(Wa2[3 * u + 1], Wa2[3 * u + 2]);
    } else if (t < 192) {
        int u = t - 128;
        float s0 = 0.f, s1 = 0.f, s2 = 0.f;
        for (int j = 0; j < 27; ++j) {
            float w = Wa1[j * 64 + u];
            s0 = fmaf(Wapp[j], w, s0);
            s1 = fmaf(Wapp[27 + j], w, s1);
            s2 = fmaf(Wapp[54 + j], w, s2);
        }
        apAs[u] = make_float4(s0, s1, s2, Wa2[3 * u]);
    } else {
        for (int job = t - 192; job < 80; job += 64) {
            if (job < 60) {
                int m = job / 20, s = job % 20;
                float a = 0.f;
                for (int k = 0; k < 32; ++k) a = fmaf(Wsf[m * 32 + k], Wsm[k * 20 + s], a);
                wscs[job] = a;
            } else {
                bsmS[job - 60] = bsm[job - 60];
            }
        }
    }

    // ray (wave-uniform)
    const float o0 = rays[r * 6 + 0], o1 = rays[r * 6 + 1], o2 = rays[r * 6 + 2];
    const float d0 = rays[r * 6 + 3], d1 = rays[r * 6 + 4], d2 = rays[r * 6 + 5];

    // t_min -- replicate numpy f32 rounding exactly (knife-edge: sample 0 on box face)
    float tm;
    {
        float v0 = (d0 == 0.f) ? 1e-6f : d0;
        float v1 = (d1 == 0.f) ? 1e-6f : d1;
        float v2 = (d2 == 0.f) ? 1e-6f : d2;
        float a0 = __fdiv_rn(__fsub_rn(1.5f, o0), v0), b0 = __fdiv_rn(__fsub_rn(-1.5f, o0), v0);
        float a1 = __fdiv_rn(__fsub_rn(1.5f, o1), v1), b1 = __fdiv_rn(__fsub_rn(-1.5f, o1), v1);
        float a2 = __fdiv_rn(__fsub_rn(1.5f, o2), v2), b2 = __fdiv_rn(__fsub_rn(-1.5f, o2), v2);
        float m0 = fminf(a0, b0), m1 = fminf(a1, b1), m2 = fminf(a2, b2);
        tm = fmaxf(fmaxf(m0, m1), m2);
        tm = fminf(fmaxf(tm, 0.05f), 6.0f);
    }

    // per-ray appearance dconst for unit==lane (lane-distributed; broadcast via readlane)
    float dcr;
    {
        float b = ba1[lane];
        b = fmaf(d0, Wa1[27 * 64 + lane], b);
        b = fmaf(d1, Wa1[28 * 64 + lane], b);
        b = fmaf(d2, Wa1[29 * 64 + lane], b);
        dcr = b;
    }

    const float bd2c = bd2[0];
    const float ba2c0 = ba2[0], ba2c1 = ba2[1], ba2c2 = ba2[2];

    __syncthreads();

    const float STEPF = (float)(3.0 / 299.001 * 3.0);
    const float zlast2 = __fadd_rn(tm, __fmul_rn(171.f, STEPF));

    float aR0 = 0.f, aR1 = 0.f, aR2 = 0.f;
    float aS0 = 0.f, aS1 = 0.f, aS2 = 0.f;
    float aSw = 0.f;
    float aD = 0.f, aLu = 0.f, aLb = 0.f;
    float Tc = 1.f, Wcar = 0.f, WMc = 0.f;

    // ---- 3 chunks of 64 samples; wave-uniform early exit (T collapses ~sample 30) ----
    for (int c = 0; c < 3; ++c) {
        int i = (c << 6) + lane;
        bool valid = i < NSAMP;
        float z = __fadd_rn(tm, __fmul_rn((float)i, STEPF));
        float x0 = __fadd_rn(o0, __fmul_rn(d0, z));
        float x1 = __fadd_rn(o1, __fmul_rn(d1, z));
        float x2 = __fadd_rn(o2, __fmul_rn(d2, z));
        bool inbox = valid && (x0 >= -1.5f) && (x0 <= 1.5f) && (x1 >= -1.5f) && (x1 <= 1.5f) &&
                     (x2 >= -1.5f) && (x2 <= 1.5f);
        if (__ballot(inbox) == 0ull) break;  // in-box span is contiguous from sample 0

        float xn0 = x0 * (2.f / 3.f), xn1 = x1 * (2.f / 3.f), xn2 = x2 * (2.f / 3.f);

        // density MLP (LDS broadcast weights)
        float sp = bd2c;
#pragma unroll 8
        for (int u = 0; u < 64; ++u) {
            float4 q = qd4[u];
            float h = fmaf(xn0, q.x, fmaf(xn1, q.y, fmaf(xn2, q.z, q.w)));
            sp = fmaf(fmaxf(h, 0.f), wd2s[u], sp);
        }
        float sigma = inbox ? softplus_f(sp) : 0.f;

        float znext = __fadd_rn(tm, __fmul_rn((float)(i + 1), STEPF));
        float dist = (i < LASTI) ? __fsub_rn(znext, z) : 0.f;
        float alpha = 1.f - __expf(-sigma * dist * 25.f);
        float f = 1.f - alpha + 1e-10f;

        // DPP product scan
        float p = scan_mul64(f);
        float pex = updpp<0x138, 0xf, false>(1.f, p);  // wave_shr1, lane0 -> 1
        float T = Tc * pex;
        float w = alpha * T;

        float mid = (i < LASTI) ? 0.5f * __fadd_rn(z, znext) : zlast2;
        float wm = w * mid;

        // DPP sum scans
        float sw = scan_add64(w);
        float swm = scan_add64(wm);
        float wex = updpp<0x138, 0xf, true>(0.f, sw);
        float wmex = updpp<0x138, 0xf, true>(0.f, swm);

        aLb += wm * (Wcar + wex) - w * (WMc + wmex);
        aLu = fmaf(dist * w, w, aLu);
        aD = fmaf(w, z, aD);

        Tc *= RL(p, 63);
        Wcar += RL(sw, 63);
        WMc += RL(swm, 63);

        // appearance (only where w > W_THRES)
        float wapp = (w > 1e-4f) ? w : 0.f;
        if (__ballot(wapp > 0.f) != 0ull) {
            float c0 = 0.f, c1 = 0.f, c2 = 0.f;
#pragma unroll 8
            for (int u = 0; u < 64; ++u) {
                float4 A4 = apAs[u];
                float2 B2 = apBs[u];
                float dcu = RL(dcr, u);
                float h = fmaf(xn0, A4.x, fmaf(xn1, A4.y, fmaf(xn2, A4.z, dcu)));
                h = fmaxf(h, 0.f);
                c0 = fmaf(h, A4.w, c0);
                c1 = fmaf(h, B2.x, c1);
                c2 = fmaf(h, B2.y, c2);
            }
            aR0 = fmaf(wapp, sigmoid_f(c0 + ba2c0), aR0);
            aR1 = fmaf(wapp, sigmoid_f(c1 + ba2c1), aR1);
            aR2 = fmaf(wapp, sigmoid_f(c2 + ba2c2), aR2);
            aS0 = fmaf(wapp, xn0, aS0);
            aS1 = fmaf(wapp, xn1, aS1);
            aS2 = fmaf(wapp, xn2, aS2);
            aSw += wapp;
        }

        if (Tc < 1e-8f) break;  // all later weights < 1e-8 << W_THRES
    }

    // wave reductions (DPP scan + readlane)
    aR0 = wave_sum64(aR0); aR1 = wave_sum64(aR1); aR2 = wave_sum64(aR2);
    aS0 = wave_sum64(aS0); aS1 = wave_sum64(aS1); aS2 = wave_sum64(aS2);
    aSw = wave_sum64(aSw);
    aD = wave_sum64(aD);
    aLu = wave_sum64(aLu);
    aLb = wave_sum64(aLb);

    float opac = Wcar;
    int wb = *whitebg_p;
    float bg = wb ? (1.f - opac) : 0.f;

    float* out_rgb = out;
    float* out_sem = out + 24576;
    float* out_inst = out + 188416;
    float* out_dep = out + 319488;

    if (lane < 3) {
        float rv = (lane == 0 ? aR0 : (lane == 1 ? aR1 : aR2)) + bg;
        rv = fminf(fmaxf(rv, 0.f), 1.f);
        out_rgb[r * 3 + lane] = rv;
    }
    if (lane < 20) {
        float sv = aS0 * wscs[lane] + aS1 * wscs[20 + lane] + aS2 * wscs[40 + lane] +
                   aSw * bsmS[lane];
        out_sem[r * 20 + lane] = sv;
    }
    if (lane < 16) {
        float iv = aS0 * Wi[lane] + aS1 * Wi[16 + lane] + aS2 * Wi[32 + lane];
        out_inst[r * 16 + lane] = iv;
    }
    if (lane == 0) {
        out_dep[r] = aD;
        wsdist[r] = aLu * (1.f / 3.f) + 2.f * aLb;
    }
}

__global__ void reduce_dist_kernel(const float* __restrict__ ws, float* __restrict__ out) {
    __shared__ float sm[256];
    int t = threadIdx.x;
    float a = 0.f;
    const float4* w4 = (const float4*)ws;
    for (int i = t; i < NRAYS / 4; i += 256) {
        float4 v = w4[i];
        a += (v.x + v.y) + (v.z + v.w);
    }
    sm[t] = a;
    __syncthreads();
    for (int st = 128; st > 0; st >>= 1) {
        if (t < st) sm[t] += sm[t + st];
        __syncthreads();
    }
    if (t == 0) out[0] = sm[0] * (1.f / (float)NRAYS);
}

extern "C" void kernel_launch(void* const* d_in, const int* in_sizes, int n_in,
                              void* d_out, int out_size, void* d_ws, size_t ws_size,
                              hipStream_t stream) {
    const float* rays = (const float*)d_in[0];
    const float* Wd1  = (const float*)d_in[1];
    const float* bd1  = (const float*)d_in[2];
    const float* Wd2  = (const float*)d_in[3];
    const float* bd2  = (const float*)d_in[4];
    const float* Wapp = (const float*)d_in[5];
    const float* Wa1  = (const float*)d_in[6];
    const float* ba1  = (const float*)d_in[7];
    const float* Wa2  = (const float*)d_in[8];
    const float* ba2  = (const float*)d_in[9];
    const float* Wsf  = (const float*)d_in[10];
    const float* Wsm  = (const float*)d_in[11];
    const float* bsm  = (const float*)d_in[12];
    const float* Wi   = (const float*)d_in[13];
    const int* wb     = (const int*)d_in[15];

    float* out = (float*)d_out;
    float* wsd = (float*)d_ws;   // 8192 f32 per-ray dist values

    render_kernel<<<NBLK, 256, 0, stream>>>(rays, Wd1, bd1, Wd2, bd2, Wapp, Wa1, ba1,
                                            Wa2, ba2, Wsf, Wsm, bsm, Wi, wb, out, wsd);
    reduce_dist_kernel<<<1, 256, 0, stream>>>(wsd, out + 327680);
}